// Round 5
// baseline (53146.155 us; speedup 1.0000x reference)
//
#include <hip/hip_runtime.h>
#include <math.h>

// Problem constants
#define NB   2048   // batch
#define SEQ  64
#define CIN  142
#define DM   256
#define NH   8
#define DHD  32
#define FFD  512
#define NL   3
#define ED   128
#define KCB  1024
#define TT   65     // SEQ+1 (cls prepended)
#define NT   512    // threads per block

__device__ __forceinline__ float gelu_f(float x) {
  return 0.5f * x * (1.0f + erff(x * 0.70710678118654752f));
}

__device__ __forceinline__ float wave_bsum(float v) {
#pragma unroll
  for (int off = 32; off >= 1; off >>= 1) v += __shfl_xor(v, off, 64);
  return v;
}
__device__ __forceinline__ float wave_bmax(float v) {
#pragma unroll
  for (int off = 32; off >= 1; off >>= 1) v = fmaxf(v, __shfl_xor(v, off, 64));
  return v;
}

// Register-tile GEMM: out[t][o] += sum_k src[t*sld+k] * Wg[grow(o)*wld + k]
// o = og + 32*oj (oj < OJN), t = tg + 16*i (t < TROWS). grow = rbase + (o&31) + rsel*(o>>5).
// Weights staged per 32-k chunk into Wst[row][36] (16B-aligned rows -> float4 LDS
// reads). No register prefetch: R2/R3 lesson — extra prefetch regs push past the
// 128-VGPR cap and cause ~80 GB/dispatch scratch spill. The round-5 invariant is
// that callers never keep a second acc[5][4] live across a gemm_accum call.
template <int OJN, int TROWS>
__device__ __forceinline__ void gemm_accum(float acc[5][4],
                                           const float* __restrict__ Wg, int wld,
                                           int rbase, int rsel,
                                           const float* src, int sld, int kdim,
                                           float* Wst, int tid) {
  constexpr int IN = (TROWS + 15) / 16;
  const int og = tid & 31, tg = tid >> 5;
  constexpr int WROWS = 32 * OJN;
  for (int kc = 0; kc < kdim; kc += 32) {
    const int kw = (kdim - kc < 32) ? (kdim - kc) : 32;
    __syncthreads();  // protect Wst from previous consumers
    if (kw == 32) {
      for (int f = tid; f < WROWS * 32; f += NT) {
        int r = f >> 5, c = f & 31;
        int grow = rbase + (r & 31) + rsel * (r >> 5);
        Wst[r * 36 + c] = Wg[grow * wld + kc + c];
      }
    } else {
      for (int f = tid; f < WROWS * kw; f += NT) {
        int r = f / kw, c = f - r * kw;
        int grow = rbase + (r & 31) + rsel * (r >> 5);
        Wst[r * 36 + c] = Wg[grow * wld + kc + c];
      }
    }
    __syncthreads();
    if (kw == 32) {
#pragma unroll
      for (int k = 0; k < 32; k += 4) {
        float4 wv[OJN];
#pragma unroll
        for (int oj = 0; oj < OJN; ++oj)
          wv[oj] = *(const float4*)&Wst[(og + 32 * oj) * 36 + k];
#pragma unroll
        for (int i = 0; i < IN; ++i) {
          int t = tg + 16 * i;
          if (i < IN - 1 || t < TROWS) {
            float4 hv = *(const float4*)&src[t * sld + kc + k];
#pragma unroll
            for (int oj = 0; oj < OJN; ++oj)
              acc[i][oj] += hv.x * wv[oj].x + hv.y * wv[oj].y +
                            hv.z * wv[oj].z + hv.w * wv[oj].w;
          }
        }
      }
    } else {  // tail (only embed: kw=14, even) - float2 path
      for (int k = 0; k < kw; k += 2) {
        float2 wv[OJN];
#pragma unroll
        for (int oj = 0; oj < OJN; ++oj)
          wv[oj] = *(const float2*)&Wst[(og + 32 * oj) * 36 + k];
#pragma unroll
        for (int i = 0; i < IN; ++i) {
          int t = tg + 16 * i;
          if (i < IN - 1 || t < TROWS) {
            float2 hv = *(const float2*)&src[t * sld + kc + k];
#pragma unroll
            for (int oj = 0; oj < OJN; ++oj)
              acc[i][oj] += hv.x * wv[oj].x + hv.y * wv[oj].y;
          }
        }
      }
    }
  }
}

__device__ __forceinline__ void ln_rows(float* buf, const float* g, const float* be,
                                        int wave, int lane) {
  for (int t = wave; t < TT; t += 8) {
    float v0 = buf[t * DM + lane],       v1 = buf[t * DM + lane + 64];
    float v2 = buf[t * DM + lane + 128], v3 = buf[t * DM + lane + 192];
    float m = wave_bsum(v0 + v1 + v2 + v3) * (1.0f / 256.0f);
    float d0 = v0 - m, d1 = v1 - m, d2 = v2 - m, d3 = v3 - m;
    float var = wave_bsum(d0 * d0 + d1 * d1 + d2 * d2 + d3 * d3) * (1.0f / 256.0f);
    float rstd = 1.0f / sqrtf(var + 1e-5f);
    buf[t * DM + lane]       = d0 * rstd * g[lane]       + be[lane];
    buf[t * DM + lane + 64]  = d1 * rstd * g[lane + 64]  + be[lane + 64];
    buf[t * DM + lane + 128] = d2 * rstd * g[lane + 128] + be[lane + 128];
    buf[t * DM + lane + 192] = d3 * rstd * g[lane + 192] + be[lane + 192];
  }
}

__global__ void vqvae_zero(float* __restrict__ ws) {
  int i = blockIdx.x * blockDim.x + threadIdx.x;
  if (i < 1025) ws[i] = 0.f;
}

// LDS (160,256 B) limits to 1 block/CU = 8 waves = 2 waves/SIMD.
// amdgpu_waves_per_eu(2) asks the allocator for at most the 2-wave budget
// (256 VGPR). Kernel is also shaped to fit 128 if the attr is ignored.
__global__ __attribute__((amdgpu_flat_work_group_size(512, 512), amdgpu_waves_per_eu(2)))
void vqvae_main(
    const float* __restrict__ x, const float* __restrict__ W_in,
    const float* __restrict__ b_in, const float* __restrict__ cls_token,
    const float* __restrict__ Wqkv, const float* __restrict__ bqkv,
    const float* __restrict__ Wo, const float* __restrict__ bo,
    const float* __restrict__ W1, const float* __restrict__ b1,
    const float* __restrict__ W2, const float* __restrict__ b2,
    const float* __restrict__ ln1_g, const float* __restrict__ ln1_b,
    const float* __restrict__ ln2_g, const float* __restrict__ ln2_b,
    const float* __restrict__ lnf_g, const float* __restrict__ lnf_b,
    const float* __restrict__ W_out, const float* __restrict__ b_out,
    const float* __restrict__ codebook, const float* __restrict__ Wd1,
    const float* __restrict__ bd1, const float* __restrict__ lnd_g,
    const float* __restrict__ lnd_b, const float* __restrict__ Wd2,
    const float* __restrict__ bd2, const float* __restrict__ Wd3,
    const float* __restrict__ bd3, float* __restrict__ out,
    float* __restrict__ ws) {
  // 160,192 B static LDS (gfx950: 163,840 B available)
  __shared__ __align__(16) float hbuf[TT * DM];  // residual stream; later: codebook chunk [128][129]
  __shared__ __align__(16) float obuf[TT * DM];  // x-stage / attn-out / FF slotA+slotB / head scalars
  __shared__ __align__(16) float scr[6768];      // Wstage [<=128][36] | qkv col-major [96][65] + p rows

  const int tid = threadIdx.x;
  const int b = blockIdx.x;
  const int lane = tid & 63, wave = tid >> 6;
  const int og = tid & 31, tg = tid >> 5;

  // ---------------- embed: h[0]=cls, h[1+r] = x[r] @ W_in^T + b_in + PE[r] ----------------
  for (int f = tid; f < SEQ * CIN; f += NT) {  // stage x[b] into obuf, rows padded to 144
    int r = f / CIN, c = f - r * CIN;
    obuf[r * 144 + c] = x[(size_t)b * (SEQ * CIN) + f];
  }
  if (tid < DM) hbuf[tid] = cls_token[tid];
  __syncthreads();

  for (int oc = 0; oc < 2; ++oc) {
    float acc[5][4] = {{0.f}};
    gemm_accum<4, 64>(acc, W_in, CIN, oc * 128, 32, obuf, 144, CIN, scr, tid);
#pragma unroll
    for (int i = 0; i < 4; ++i) {
      int r = tg + 16 * i;
#pragma unroll
      for (int oj = 0; oj < 4; ++oj) {
        int d = oc * 128 + og + 32 * oj;
        float div = expf(-(float)(d & ~1) * (9.210340371976184f / 256.0f));
        float ang = (float)r * div;
        float pe = (d & 1) ? cosf(ang) : sinf(ang);
        hbuf[(r + 1) * DM + d] = acc[i][oj] + b_in[d] + pe;
      }
    }
  }
  __syncthreads();

  // ---------------- transformer layers ----------------
  for (int li = 0; li < NL; ++li) {
    const float* Wqkv_l = Wqkv + (size_t)li * 768 * DM;
    const float* bqkv_l = bqkv + li * 768;
    const float* Wo_l = Wo + (size_t)li * DM * DM;
    const float* bo_l = bo + li * DM;
    const float* W1_l = W1 + (size_t)li * FFD * DM;
    const float* b1_l = b1 + li * FFD;
    const float* W2_l = W2 + (size_t)li * DM * FFD;
    const float* b2_l = b2 + li * DM;

    // ---- attention (per head): qkv GEMM -> col-major scr, online softmax, o -> obuf ----
    for (int hd = 0; hd < NH; ++hd) {
      float acc[5][4] = {{0.f}};
      // rows: q=hd*32+og (oj=0), k=256+hd*32+og (oj=1), v=512+hd*32+og (oj=2)
      gemm_accum<3, 65>(acc, Wqkv_l, DM, hd * 32, 256, hbuf, DM, DM, scr, tid);
      __syncthreads();  // all Wst reads done before qkv overwrites scr
#pragma unroll
      for (int i = 0; i < 5; ++i) {
        int t = tg + 16 * i;
        if (t < TT) {
#pragma unroll
          for (int oj = 0; oj < 3; ++oj)
            scr[(og + 32 * oj) * TT + t] = acc[i][oj] + bqkv_l[oj * 256 + hd * 32 + og];
        }
      }
      __syncthreads();

      // scores: lane=u(0..63), rows t = wave+8*it; u=64 handled via reduced partial
      float sv[9];
#pragma unroll
      for (int it = 0; it < 9; ++it) sv[it] = 0.f;
#pragma unroll 4
      for (int j = 0; j < 32; ++j) {
        float kv = scr[(32 + j) * TT + lane];  // k[lane][j]
#pragma unroll
        for (int it = 0; it < 9; ++it) {
          int t = wave + 8 * it;
          if (it < 8 || t < TT) sv[it] += scr[j * TT + t] * kv;  // q[t][j] broadcast
        }
      }
#pragma unroll
      for (int it = 0; it < 9; ++it) {
        int t = wave + 8 * it;
        if (t < TT) {  // wave-uniform guard
          int jj = lane & 31;
          float p64 = scr[jj * TT + t] * scr[(32 + jj) * TT + 64] * 0.5f;  // halves dup -> *0.5
          p64 = wave_bsum(p64);
          const float sc = 0.17677669529663687f;  // 1/sqrt(32)
          float s = sv[it] * sc, s64 = p64 * sc;
          float m = fmaxf(wave_bmax(s), s64);
          float e = expf(s - m), e64 = expf(s64 - m);
          float inv = 1.0f / (wave_bsum(e) + e64);
          float* prow = &scr[96 * TT + wave * 66];
          prow[lane] = e * inv;
          if (lane == 0) prow[64] = e64 * inv;
          // o[t][e] = sum_u p[u] * v[u][e]; lanes (e, u-half)
          int e_ = lane & 31, half = lane >> 5;
          float o = 0.f;
          int u0 = half * 33, u1 = half ? 65 : 33;
#pragma unroll 4
          for (int u = u0; u < u1; ++u) o += prow[u] * scr[(64 + e_) * TT + u];
          o += __shfl_down(o, 32, 64);
          if (lane < 32) obuf[t * DM + hd * 32 + e_] = o;
        }
      }
      __syncthreads();  // before next head re-stages scr
    }

    // ---- proj + residual: h += o @ Wo^T + bo ; LN1 ----
    for (int oc = 0; oc < 2; ++oc) {
      float acc[5][4] = {{0.f}};
      gemm_accum<4, 65>(acc, Wo_l, DM, oc * 128, 32, obuf, DM, DM, scr, tid);
#pragma unroll
      for (int i = 0; i < 5; ++i) {
        int t = tg + 16 * i;
        if (t < TT) {
#pragma unroll
          for (int oj = 0; oj < 4; ++oj) {
            int d = oc * 128 + og + 32 * oj;
            hbuf[t * DM + d] += acc[i][oj] + bo_l[d];
          }
        }
      }
    }
    __syncthreads();
    ln_rows(hbuf, ln1_g + li * DM, ln1_b + li * DM, wave, lane);
    __syncthreads();

    // ---- FF, register-pressure-shaped ----
    // u = ln1 output (hbuf), preserved until the end. f1 hidden blocks (4 x 128)
    // recomputed per output chunk (+7.5% FLOPs) so only ONE acc[5][4] set is live
    // in any gemm. ff chunk0 accumulates in LDS (slotB, residual+bias folded into
    // init); ff chunk1 in racc registers.
    float* slotA = obuf;             // f1 block [65][128]
    float* slotB = obuf + TT * 128;  // ff chunk0 accumulator [65][128]
    for (int f = tid; f < TT * 128; f += NT) {
      int t = f >> 7, dl = f & 127;
      slotB[f] = hbuf[t * DM + dl] + b2_l[dl];
    }
    float racc[5][4];
#pragma unroll
    for (int i = 0; i < 5; ++i) {
      int t = tg + 16 * i;
#pragma unroll
      for (int oj = 0; oj < 4; ++oj)
        racc[i][oj] = (t < TT) ? hbuf[t * DM + 128 + og + 32 * oj] + b2_l[128 + og + 32 * oj]
                               : 0.f;
    }
    for (int oc = 0; oc < 2; ++oc) {
      for (int hb = 0; hb < 4; ++hb) {
        {  // f1_hb = gelu(u @ W1_hb^T + b1_hb) -> slotA
          float acc[5][4] = {{0.f}};
          gemm_accum<4, 65>(acc, W1_l, DM, hb * 128, 32, hbuf, DM, DM, scr, tid);
          // safe without extra barrier: prior slotA readers fenced by this gemm's
          // internal barriers; concurrent threads only read hbuf/Wst here.
#pragma unroll
          for (int i = 0; i < 5; ++i) {
            int t = tg + 16 * i;
            if (t < TT) {
#pragma unroll
              for (int oj = 0; oj < 4; ++oj) {
                int j = og + 32 * oj;
                slotA[t * 128 + j] = gelu_f(acc[i][oj] + b1_l[hb * 128 + j]);
              }
            }
          }
        }
        // W2 partial over this hidden block (K=128); W2 col offset = hb*128
        if (oc == 0) {
          float acc[5][4] = {{0.f}};
          gemm_accum<4, 65>(acc, W2_l + hb * 128, FFD, 0, 32, slotA, 128, 128, scr, tid);
#pragma unroll
          for (int i = 0; i < 5; ++i) {
            int t = tg + 16 * i;
            if (t < TT) {
#pragma unroll
              for (int oj = 0; oj < 4; ++oj)
                slotB[t * 128 + og + 32 * oj] += acc[i][oj];  // own slot, no race
            }
          }
        } else {
          gemm_accum<4, 65>(racc, W2_l + hb * 128, FFD, 128, 32, slotA, 128, 128, scr, tid);
        }
      }
    }
    __syncthreads();  // all hbuf/slotA/slotB reads complete
#pragma unroll
    for (int i = 0; i < 5; ++i) {
      int t = tg + 16 * i;
      if (t < TT) {
#pragma unroll
        for (int oj = 0; oj < 4; ++oj) {
          int j = og + 32 * oj;
          hbuf[t * DM + j] = slotB[t * 128 + j];
          hbuf[t * DM + 128 + j] = racc[i][oj];
        }
      }
    }
    __syncthreads();
    ln_rows(hbuf, ln2_g + li * DM, ln2_b + li * DM, wave, lane);
    __syncthreads();
  }

  // ---------------- head: lnf(cls) -> z_e -> VQ argmin -> decoder ----------------
  if (tid < 64) {  // lnf on row 0 -> obuf[0..255]
    float v0 = hbuf[lane], v1 = hbuf[lane + 64], v2 = hbuf[lane + 128], v3 = hbuf[lane + 192];
    float m = wave_bsum(v0 + v1 + v2 + v3) * (1.0f / 256.0f);
    float d0 = v0 - m, d1 = v1 - m, d2 = v2 - m, d3 = v3 - m;
    float var = wave_bsum(d0 * d0 + d1 * d1 + d2 * d2 + d3 * d3) * (1.0f / 256.0f);
    float rstd = 1.0f / sqrtf(var + 1e-5f);
    obuf[lane]       = d0 * rstd * lnf_g[lane]       + lnf_b[lane];
    obuf[lane + 64]  = d1 * rstd * lnf_g[lane + 64]  + lnf_b[lane + 64];
    obuf[lane + 128] = d2 * rstd * lnf_g[lane + 128] + lnf_b[lane + 128];
    obuf[lane + 192] = d3 * rstd * lnf_g[lane + 192] + lnf_b[lane + 192];
  }
  __syncthreads();
  // z_e = lnf(cls) @ W_out^T + b_out -> obuf[256..384)
  for (int o = wave; o < ED; o += 8) {
    const float4 w4 = *(const float4*)&W_out[o * DM + lane * 4];
    const float4 c4 = *(const float4*)&obuf[lane * 4];
    float s = w4.x * c4.x + w4.y * c4.y + w4.z * c4.z + w4.w * c4.w;
    s = wave_bsum(s);
    if (lane == 0) obuf[256 + o] = s + b_out[o];
  }
  __syncthreads();

  // VQ argmin over |cb|^2 - 2 ze.cb (|ze|^2 constant); first-index tie-break
  float bestv = 3.4e38f;
  int bestk = 0;
  for (int ch = 0; ch < 8; ++ch) {
    __syncthreads();
    for (int f = tid; f < 128 * 128; f += NT) {  // stage cb chunk, rows padded to 129
      int r = f >> 7, c = f & 127;
      hbuf[r * 129 + c] = codebook[(size_t)(ch * 128 + r) * ED + c];
    }
    __syncthreads();
    {
      int kl = tid & 127, q = tid >> 7;
      float part = 0.f;
#pragma unroll 8
      for (int jj = 0; jj < 32; ++jj) {
        int e = q * 32 + jj;
        float cv = hbuf[kl * 129 + e];
        part += cv * (cv - 2.0f * obuf[256 + e]);
      }
      scr[kl * 4 + q] = part;
    }
    __syncthreads();
    if (tid < 128) {
      float d2v = scr[tid * 4] + scr[tid * 4 + 1] + scr[tid * 4 + 2] + scr[tid * 4 + 3];
      int kk = ch * 128 + tid;
      if (d2v < bestv) { bestv = d2v; bestk = kk; }  // ascending k per thread
    }
  }
  if (tid < 128) {
    scr[512 + tid] = bestv;
    scr[640 + tid] = __int_as_float(bestk);
  }
  __syncthreads();
  if (tid == 0) {
    float bv = 3.4e38f;
    int bk = 1 << 30;
    for (int j = 0; j < 128; ++j) {
      float v = scr[512 + j];
      int kk = __float_as_int(scr[640 + j]);
      if (v < bv || (v == bv && kk < bk)) { bv = v; bk = kk; }
    }
    scr[700] = __int_as_float(bk);
    out[2 * NB + b] = (float)bk;  // indices output (as float value)
  }
  __syncthreads();
  const int bk = __float_as_int(scr[700]);

  // z_q -> obuf[384..512); commitment + histogram
  if (tid < ED) {
    float zqv = codebook[(size_t)bk * ED + tid];
    obuf[384 + tid] = zqv;
    float df = zqv - obuf[256 + tid];
    float sq = wave_bsum(df * df);
    if ((tid & 63) == 0) atomicAdd(&ws[0], sq);
  }
  if (tid == 0) atomicAdd(&ws[1 + bk], 1.0f);
  __syncthreads();

  // decoder: d1 = zq @ Wd1^T + bd1 (256) -> LN -> gelu -> @Wd2^T (128) -> gelu -> @Wd3^T (2)
  for (int o = wave; o < DM; o += 8) {
    const float2 w2 = *(const float2*)&Wd1[o * ED + lane * 2];
    const float2 z2 = *(const float2*)&obuf[384 + lane * 2];
    float s = wave_bsum(w2.x * z2.x + w2.y * z2.y);
    if (lane == 0) obuf[512 + o] = s + bd1[o];
  }
  __syncthreads();
  if (tid < 64) {
    float v0 = obuf[512 + lane], v1 = obuf[512 + lane + 64];
    float v2 = obuf[512 + lane + 128], v3 = obuf[512 + lane + 192];
    float m = wave_bsum(v0 + v1 + v2 + v3) * (1.0f / 256.0f);
    float d0 = v0 - m, d1 = v1 - m, d2 = v2 - m, d3 = v3 - m;
    float var = wave_bsum(d0 * d0 + d1 * d1 + d2 * d2 + d3 * d3) * (1.0f / 256.0f);
    float rstd = 1.0f / sqrtf(var + 1e-5f);
    obuf[512 + lane]       = gelu_f(d0 * rstd * lnd_g[lane]       + lnd_b[lane]);
    obuf[512 + lane + 64]  = gelu_f(d1 * rstd * lnd_g[lane + 64]  + lnd_b[lane + 64]);
    obuf[512 + lane + 128] = gelu_f(d2 * rstd * lnd_g[lane + 128] + lnd_b[lane + 128]);
    obuf[512 + lane + 192] = gelu_f(d3 * rstd * lnd_g[lane + 192] + lnd_b[lane + 192]);
  }
  __syncthreads();
  for (int o = wave; o < ED; o += 8) {
    const float4 w4 = *(const float4*)&Wd2[o * DM + lane * 4];
    const float4 g4 = *(const float4*)&obuf[512 + lane * 4];
    float s = wave_bsum(w4.x * g4.x + w4.y * g4.y + w4.z * g4.z + w4.w * g4.w);
    if (lane == 0) obuf[768 + o] = gelu_f(s + bd2[o]);
  }
  __syncthreads();
  if (wave < 2) {
    const float2 w2 = *(const float2*)&Wd3[wave * ED + lane * 2];
    const float2 g2 = *(const float2*)&obuf[768 + lane * 2];
    float s = wave_bsum(w2.x * g2.x + w2.y * g2.y);
    if (lane == 0) out[b * 2 + wave] = s + bd3[wave];
  }
}

__global__ void vqvae_finish(const float* __restrict__ ws, float* __restrict__ out) {
  __shared__ float red[256];
  int tid = threadIdx.x;
  float part = 0.f;
  for (int k = tid; k < KCB; k += 256) {
    float p = ws[1 + k] * (1.0f / 2048.0f);
    part += p * logf(p + 1e-10f);
  }
  red[tid] = part;
  __syncthreads();
  for (int s = 128; s > 0; s >>= 1) {
    if (tid < s) red[tid] += red[tid + s];
    __syncthreads();
  }
  if (tid == 0) {
    out[2 * NB + NB]     = 0.1f * ws[0] * (1.0f / (2048.0f * 128.0f));  // commitment loss
    out[2 * NB + NB + 1] = expf(-red[0]);                               // perplexity
  }
}

extern "C" void kernel_launch(void* const* d_in, const int* in_sizes, int n_in,
                              void* d_out, int out_size, void* d_ws, size_t ws_size,
                              hipStream_t stream) {
  (void)in_sizes; (void)n_in; (void)out_size; (void)ws_size;
  const float* x         = (const float*)d_in[0];
  const float* W_in      = (const float*)d_in[1];
  const float* b_in      = (const float*)d_in[2];
  const float* cls_token = (const float*)d_in[3];
  const float* Wqkv      = (const float*)d_in[4];
  const float* bqkv      = (const float*)d_in[5];
  const float* Wo        = (const float*)d_in[6];
  const float* bo        = (const float*)d_in[7];
  const float* W1        = (const float*)d_in[8];
  const float* b1        = (const float*)d_in[9];
  const float* W2        = (const float*)d_in[10];
  const float* b2        = (const float*)d_in[11];
  const float* ln1_g     = (const float*)d_in[12];
  const float* ln1_b     = (const float*)d_in[13];
  const float* ln2_g     = (const float*)d_in[14];
  const float* ln2_b     = (const float*)d_in[15];
  const float* lnf_g     = (const float*)d_in[16];
  const float* lnf_b     = (const float*)d_in[17];
  const float* W_out     = (const float*)d_in[18];
  const float* b_out     = (const float*)d_in[19];
  const float* codebook  = (const float*)d_in[20];
  const float* Wd1       = (const float*)d_in[21];
  const float* bd1       = (const float*)d_in[22];
  const float* lnd_g     = (const float*)d_in[23];
  const float* lnd_b     = (const float*)d_in[24];
  const float* Wd2       = (const float*)d_in[25];
  const float* bd2       = (const float*)d_in[26];
  const float* Wd3       = (const float*)d_in[27];
  const float* bd3       = (const float*)d_in[28];
  float* out = (float*)d_out;
  float* ws = (float*)d_ws;

  hipLaunchKernelGGL(vqvae_zero, dim3(5), dim3(256), 0, stream, ws);
  hipLaunchKernelGGL(vqvae_main, dim3(NB), dim3(NT), 0, stream,
                     x, W_in, b_in, cls_token, Wqkv, bqkv, Wo, bo, W1, b1, W2, b2,
                     ln1_g, ln1_b, ln2_g, ln2_b, lnf_g, lnf_b, W_out, b_out,
                     codebook, Wd1, bd1, lnd_g, lnd_b, Wd2, bd2, Wd3, bd3, out, ws);
  hipLaunchKernelGGL(vqvae_finish, dim3(1), dim3(256), 0, stream, ws, out);
}

// Round 6
// 34715.030 us; speedup vs baseline: 1.5309x; 1.5309x over previous
//
#include <hip/hip_runtime.h>
#include <math.h>

// Problem constants
#define NB   2048   // batch
#define SEQ  64
#define CIN  142
#define DM   256
#define NH   8
#define DHD  32
#define FFD  512
#define NL   3
#define ED   128
#define KCB  1024
#define TT   65     // SEQ+1 (cls prepended)
#define NT   512    // threads per block

__device__ __forceinline__ float gelu_f(float x) {
  return 0.5f * x * (1.0f + erff(x * 0.70710678118654752f));
}

__device__ __forceinline__ float wave_bsum(float v) {
#pragma unroll
  for (int off = 32; off >= 1; off >>= 1) v += __shfl_xor(v, off, 64);
  return v;
}
__device__ __forceinline__ float wave_bmax(float v) {
#pragma unroll
  for (int off = 32; off >= 1; off >>= 1) v = fmaxf(v, __shfl_xor(v, off, 64));
  return v;
}

// Register-tile GEMM: out[t][o] += sum_k src[t*sld+k] * Wg[grow(o)*wld + k]
// o = og + 32*oj (oj < OJN), t = tg + 16*i (t < TROWS). grow = rbase + (o&31) + rsel*(o>>5).
// Weights staged per 32-k chunk into Wst[row][36] (16B-aligned rows -> float4 LDS reads).
// SPILL INVARIANT (R1-R5 lesson, quantified: ~320 B HBM scratch written per thread
// per k-chunk when violated): callers must keep NO extra register array live
// across a gemm_accum call. Only the acc being accumulated may be live.
template <int OJN, int TROWS>
__device__ __forceinline__ void gemm_accum(float acc[5][4],
                                           const float* __restrict__ Wg, int wld,
                                           int rbase, int rsel,
                                           const float* src, int sld, int kdim,
                                           float* Wst, int tid) {
  constexpr int IN = (TROWS + 15) / 16;
  const int og = tid & 31, tg = tid >> 5;
  constexpr int WROWS = 32 * OJN;
  for (int kc = 0; kc < kdim; kc += 32) {
    const int kw = (kdim - kc < 32) ? (kdim - kc) : 32;
    __syncthreads();  // protect Wst from previous consumers
    if (kw == 32) {
      for (int f = tid; f < WROWS * 32; f += NT) {
        int r = f >> 5, c = f & 31;
        int grow = rbase + (r & 31) + rsel * (r >> 5);
        Wst[r * 36 + c] = Wg[grow * wld + kc + c];
      }
    } else {
      for (int f = tid; f < WROWS * kw; f += NT) {
        int r = f / kw, c = f - r * kw;
        int grow = rbase + (r & 31) + rsel * (r >> 5);
        Wst[r * 36 + c] = Wg[grow * wld + kc + c];
      }
    }
    __syncthreads();
    if (kw == 32) {
#pragma unroll
      for (int k = 0; k < 32; k += 4) {
        float4 wv[OJN];
#pragma unroll
        for (int oj = 0; oj < OJN; ++oj)
          wv[oj] = *(const float4*)&Wst[(og + 32 * oj) * 36 + k];
#pragma unroll
        for (int i = 0; i < IN; ++i) {
          int t = tg + 16 * i;
          if (i < IN - 1 || t < TROWS) {
            float4 hv = *(const float4*)&src[t * sld + kc + k];
#pragma unroll
            for (int oj = 0; oj < OJN; ++oj)
              acc[i][oj] += hv.x * wv[oj].x + hv.y * wv[oj].y +
                            hv.z * wv[oj].z + hv.w * wv[oj].w;
          }
        }
      }
    } else {  // tail (only embed: kw=14, even) - float2 path
      for (int k = 0; k < kw; k += 2) {
        float2 wv[OJN];
#pragma unroll
        for (int oj = 0; oj < OJN; ++oj)
          wv[oj] = *(const float2*)&Wst[(og + 32 * oj) * 36 + k];
#pragma unroll
        for (int i = 0; i < IN; ++i) {
          int t = tg + 16 * i;
          if (i < IN - 1 || t < TROWS) {
            float2 hv = *(const float2*)&src[t * sld + kc + k];
#pragma unroll
            for (int oj = 0; oj < OJN; ++oj)
              acc[i][oj] += hv.x * wv[oj].x + hv.y * wv[oj].y;
          }
        }
      }
    }
  }
}

__device__ __forceinline__ void ln_rows(float* buf, const float* g, const float* be,
                                        int wave, int lane) {
  for (int t = wave; t < TT; t += 8) {
    float v0 = buf[t * DM + lane],       v1 = buf[t * DM + lane + 64];
    float v2 = buf[t * DM + lane + 128], v3 = buf[t * DM + lane + 192];
    float m = wave_bsum(v0 + v1 + v2 + v3) * (1.0f / 256.0f);
    float d0 = v0 - m, d1 = v1 - m, d2 = v2 - m, d3 = v3 - m;
    float var = wave_bsum(d0 * d0 + d1 * d1 + d2 * d2 + d3 * d3) * (1.0f / 256.0f);
    float rstd = 1.0f / sqrtf(var + 1e-5f);
    buf[t * DM + lane]       = d0 * rstd * g[lane]       + be[lane];
    buf[t * DM + lane + 64]  = d1 * rstd * g[lane + 64]  + be[lane + 64];
    buf[t * DM + lane + 128] = d2 * rstd * g[lane + 128] + be[lane + 128];
    buf[t * DM + lane + 192] = d3 * rstd * g[lane + 192] + be[lane + 192];
  }
}

__global__ void vqvae_zero(float* __restrict__ ws) {
  int i = blockIdx.x * blockDim.x + threadIdx.x;
  if (i < 1025) ws[i] = 0.f;
}

// LDS (161,216 B) limits to 1 block/CU = 8 waves = 2 waves/SIMD.
__global__ __attribute__((amdgpu_flat_work_group_size(512, 512), amdgpu_waves_per_eu(2)))
void vqvae_main(
    const float* __restrict__ x, const float* __restrict__ W_in,
    const float* __restrict__ b_in, const float* __restrict__ cls_token,
    const float* __restrict__ Wqkv, const float* __restrict__ bqkv,
    const float* __restrict__ Wo, const float* __restrict__ bo,
    const float* __restrict__ W1, const float* __restrict__ b1,
    const float* __restrict__ W2, const float* __restrict__ b2,
    const float* __restrict__ ln1_g, const float* __restrict__ ln1_b,
    const float* __restrict__ ln2_g, const float* __restrict__ ln2_b,
    const float* __restrict__ lnf_g, const float* __restrict__ lnf_b,
    const float* __restrict__ W_out, const float* __restrict__ b_out,
    const float* __restrict__ codebook, const float* __restrict__ Wd1,
    const float* __restrict__ bd1, const float* __restrict__ lnd_g,
    const float* __restrict__ lnd_b, const float* __restrict__ Wd2,
    const float* __restrict__ bd2, const float* __restrict__ Wd3,
    const float* __restrict__ bd3, float* __restrict__ out,
    float* __restrict__ ws) {
  // 161,216 B static LDS (gfx950: 163,840 B available)
  __shared__ __align__(16) float hbuf[TT * DM];  // residual stream; later: codebook chunk [128][129]
  __shared__ __align__(16) float obuf[16896];    // x-stage / attn-out / FF f1 [<=33][512] / head scalars
  __shared__ __align__(16) float scr[6768];      // Wstage [<=128][36] | qkv col-major [96][65] + p rows

  const int tid = threadIdx.x;
  const int b = blockIdx.x;
  const int lane = tid & 63, wave = tid >> 6;
  const int og = tid & 31, tg = tid >> 5;

  // ---------------- embed: h[0]=cls, h[1+r] = x[r] @ W_in^T + b_in + PE[r] ----------------
  for (int f = tid; f < SEQ * CIN; f += NT) {  // stage x[b] into obuf, rows padded to 144
    int r = f / CIN, c = f - r * CIN;
    obuf[r * 144 + c] = x[(size_t)b * (SEQ * CIN) + f];
  }
  if (tid < DM) hbuf[tid] = cls_token[tid];
  __syncthreads();

  for (int oc = 0; oc < 2; ++oc) {
    float acc[5][4] = {{0.f}};
    gemm_accum<4, 64>(acc, W_in, CIN, oc * 128, 32, obuf, 144, CIN, scr, tid);
#pragma unroll
    for (int i = 0; i < 4; ++i) {
      int r = tg + 16 * i;
#pragma unroll
      for (int oj = 0; oj < 4; ++oj) {
        int d = oc * 128 + og + 32 * oj;
        float div = expf(-(float)(d & ~1) * (9.210340371976184f / 256.0f));
        float ang = (float)r * div;
        float pe = (d & 1) ? cosf(ang) : sinf(ang);
        hbuf[(r + 1) * DM + d] = acc[i][oj] + b_in[d] + pe;
      }
    }
  }
  __syncthreads();

  // ---------------- transformer layers ----------------
  for (int li = 0; li < NL; ++li) {
    const float* Wqkv_l = Wqkv + (size_t)li * 768 * DM;
    const float* bqkv_l = bqkv + li * 768;
    const float* Wo_l = Wo + (size_t)li * DM * DM;
    const float* bo_l = bo + li * DM;
    const float* W1_l = W1 + (size_t)li * FFD * DM;
    const float* b1_l = b1 + li * FFD;
    const float* W2_l = W2 + (size_t)li * DM * FFD;
    const float* b2_l = b2 + li * DM;

    // ---- attention (per head): qkv GEMM -> col-major scr, online softmax, o -> obuf ----
    for (int hd = 0; hd < NH; ++hd) {
      float acc[5][4] = {{0.f}};
      // rows: q=hd*32+og (oj=0), k=256+hd*32+og (oj=1), v=512+hd*32+og (oj=2)
      gemm_accum<3, 65>(acc, Wqkv_l, DM, hd * 32, 256, hbuf, DM, DM, scr, tid);
      __syncthreads();  // all Wst reads done before qkv overwrites scr
#pragma unroll
      for (int i = 0; i < 5; ++i) {
        int t = tg + 16 * i;
        if (t < TT) {
#pragma unroll
          for (int oj = 0; oj < 3; ++oj)
            scr[(og + 32 * oj) * TT + t] = acc[i][oj] + bqkv_l[oj * 256 + hd * 32 + og];
        }
      }
      __syncthreads();

      // scores: lane=u(0..63), rows t = wave+8*it; u=64 handled via reduced partial
      float sv[9];
#pragma unroll
      for (int it = 0; it < 9; ++it) sv[it] = 0.f;
#pragma unroll 4
      for (int j = 0; j < 32; ++j) {
        float kv = scr[(32 + j) * TT + lane];  // k[lane][j]
#pragma unroll
        for (int it = 0; it < 9; ++it) {
          int t = wave + 8 * it;
          if (it < 8 || t < TT) sv[it] += scr[j * TT + t] * kv;  // q[t][j] broadcast
        }
      }
#pragma unroll
      for (int it = 0; it < 9; ++it) {
        int t = wave + 8 * it;
        if (t < TT) {  // wave-uniform guard
          int jj = lane & 31;
          float p64 = scr[jj * TT + t] * scr[(32 + jj) * TT + 64] * 0.5f;  // halves dup -> *0.5
          p64 = wave_bsum(p64);
          const float sc = 0.17677669529663687f;  // 1/sqrt(32)
          float s = sv[it] * sc, s64 = p64 * sc;
          float m = fmaxf(wave_bmax(s), s64);
          float e = expf(s - m), e64 = expf(s64 - m);
          float inv = 1.0f / (wave_bsum(e) + e64);
          float* prow = &scr[96 * TT + wave * 66];
          prow[lane] = e * inv;
          if (lane == 0) prow[64] = e64 * inv;
          // o[t][e] = sum_u p[u] * v[u][e]; lanes (e, u-half)
          int e_ = lane & 31, half = lane >> 5;
          float o = 0.f;
          int u0 = half * 33, u1 = half ? 65 : 33;
#pragma unroll 4
          for (int u = u0; u < u1; ++u) o += prow[u] * scr[(64 + e_) * TT + u];
          o += __shfl_down(o, 32, 64);
          if (lane < 32) obuf[t * DM + hd * 32 + e_] = o;
        }
      }
      __syncthreads();  // before next head re-stages scr
    }

    // ---- proj + residual: h += o @ Wo^T + bo ; LN1 ----
    for (int oc = 0; oc < 2; ++oc) {
      float acc[5][4] = {{0.f}};
      gemm_accum<4, 65>(acc, Wo_l, DM, oc * 128, 32, obuf, DM, DM, scr, tid);
#pragma unroll
      for (int i = 0; i < 5; ++i) {
        int t = tg + 16 * i;
        if (t < TT) {
#pragma unroll
          for (int oj = 0; oj < 4; ++oj) {
            int d = oc * 128 + og + 32 * oj;
            hbuf[t * DM + d] += acc[i][oj] + bo_l[d];
          }
        }
      }
    }
    __syncthreads();
    ln_rows(hbuf, ln1_g + li * DM, ln1_b + li * DM, wave, lane);
    __syncthreads();

    // ---- FF: T-split two-pass; ZERO registers live across any gemm ----
    // pass 0: rows [0,32). pass 1: rows [32,65).
    // f1 (full 512 hidden cols) for the pass lives in obuf [nr][512].
    // W2 then runs one K=512 sweep per 128-col output chunk, writing
    // ff + u + b2 directly into hbuf rows of this pass (disjoint from the
    // u rows the other pass's W1 still needs).
    for (int ps = 0; ps < 2; ++ps) {
      const int r0 = ps ? 32 : 0;
      const int nr = ps ? 33 : 32;
      for (int mc = 0; mc < 4; ++mc) {
        float acc[5][4] = {{0.f}};
        if (ps == 0)
          gemm_accum<4, 32>(acc, W1_l, DM, mc * 128, 32, hbuf + r0 * DM, DM, DM, scr, tid);
        else
          gemm_accum<4, 33>(acc, W1_l, DM, mc * 128, 32, hbuf + r0 * DM, DM, DM, scr, tid);
#pragma unroll
        for (int i = 0; i < 3; ++i) {
          int t = tg + 16 * i;
          if (t < nr) {
#pragma unroll
            for (int oj = 0; oj < 4; ++oj) {
              int m = mc * 128 + og + 32 * oj;
              obuf[t * FFD + m] = gelu_f(acc[i][oj] + b1_l[m]);
            }
          }
        }
      }
      for (int oc = 0; oc < 2; ++oc) {
        float acc[5][4] = {{0.f}};
        if (ps == 0)
          gemm_accum<4, 32>(acc, W2_l, FFD, oc * 128, 32, obuf, FFD, FFD, scr, tid);
        else
          gemm_accum<4, 33>(acc, W2_l, FFD, oc * 128, 32, obuf, FFD, FFD, scr, tid);
#pragma unroll
        for (int i = 0; i < 3; ++i) {
          int t = tg + 16 * i;
          if (t < nr) {
#pragma unroll
            for (int oj = 0; oj < 4; ++oj) {
              int d = oc * 128 + og + 32 * oj;
              int gi = (r0 + t) * DM + d;
              hbuf[gi] = hbuf[gi] + acc[i][oj] + b2_l[d];  // own element, no race
            }
          }
        }
      }
    }
    __syncthreads();
    ln_rows(hbuf, ln2_g + li * DM, ln2_b + li * DM, wave, lane);
    __syncthreads();
  }

  // ---------------- head: lnf(cls) -> z_e -> VQ argmin -> decoder ----------------
  if (tid < 64) {  // lnf on row 0 -> obuf[0..255]
    float v0 = hbuf[lane], v1 = hbuf[lane + 64], v2 = hbuf[lane + 128], v3 = hbuf[lane + 192];
    float m = wave_bsum(v0 + v1 + v2 + v3) * (1.0f / 256.0f);
    float d0 = v0 - m, d1 = v1 - m, d2 = v2 - m, d3 = v3 - m;
    float var = wave_bsum(d0 * d0 + d1 * d1 + d2 * d2 + d3 * d3) * (1.0f / 256.0f);
    float rstd = 1.0f / sqrtf(var + 1e-5f);
    obuf[lane]       = d0 * rstd * lnf_g[lane]       + lnf_b[lane];
    obuf[lane + 64]  = d1 * rstd * lnf_g[lane + 64]  + lnf_b[lane + 64];
    obuf[lane + 128] = d2 * rstd * lnf_g[lane + 128] + lnf_b[lane + 128];
    obuf[lane + 192] = d3 * rstd * lnf_g[lane + 192] + lnf_b[lane + 192];
  }
  __syncthreads();
  // z_e = lnf(cls) @ W_out^T + b_out -> obuf[256..384)
  for (int o = wave; o < ED; o += 8) {
    const float4 w4 = *(const float4*)&W_out[o * DM + lane * 4];
    const float4 c4 = *(const float4*)&obuf[lane * 4];
    float s = w4.x * c4.x + w4.y * c4.y + w4.z * c4.z + w4.w * c4.w;
    s = wave_bsum(s);
    if (lane == 0) obuf[256 + o] = s + b_out[o];
  }
  __syncthreads();

  // VQ argmin over |cb|^2 - 2 ze.cb (|ze|^2 constant); first-index tie-break
  float bestv = 3.4e38f;
  int bestk = 0;
  for (int ch = 0; ch < 8; ++ch) {
    __syncthreads();
    for (int f = tid; f < 128 * 128; f += NT) {  // stage cb chunk, rows padded to 129
      int r = f >> 7, c = f & 127;
      hbuf[r * 129 + c] = codebook[(size_t)(ch * 128 + r) * ED + c];
    }
    __syncthreads();
    {
      int kl = tid & 127, q = tid >> 7;
      float part = 0.f;
#pragma unroll 8
      for (int jj = 0; jj < 32; ++jj) {
        int e = q * 32 + jj;
        float cv = hbuf[kl * 129 + e];
        part += cv * (cv - 2.0f * obuf[256 + e]);
      }
      scr[kl * 4 + q] = part;
    }
    __syncthreads();
    if (tid < 128) {
      float d2v = scr[tid * 4] + scr[tid * 4 + 1] + scr[tid * 4 + 2] + scr[tid * 4 + 3];
      int kk = ch * 128 + tid;
      if (d2v < bestv) { bestv = d2v; bestk = kk; }  // ascending k per thread
    }
  }
  if (tid < 128) {
    scr[512 + tid] = bestv;
    scr[640 + tid] = __int_as_float(bestk);
  }
  __syncthreads();
  if (tid == 0) {
    float bv = 3.4e38f;
    int bk = 1 << 30;
    for (int j = 0; j < 128; ++j) {
      float v = scr[512 + j];
      int kk = __float_as_int(scr[640 + j]);
      if (v < bv || (v == bv && kk < bk)) { bv = v; bk = kk; }
    }
    scr[700] = __int_as_float(bk);
    out[2 * NB + b] = (float)bk;  // indices output (as float value)
  }
  __syncthreads();
  const int bk = __float_as_int(scr[700]);

  // z_q -> obuf[384..512); commitment + histogram
  if (tid < ED) {
    float zqv = codebook[(size_t)bk * ED + tid];
    obuf[384 + tid] = zqv;
    float df = zqv - obuf[256 + tid];
    float sq = wave_bsum(df * df);
    if ((tid & 63) == 0) atomicAdd(&ws[0], sq);
  }
  if (tid == 0) atomicAdd(&ws[1 + bk], 1.0f);
  __syncthreads();

  // decoder: d1 = zq @ Wd1^T + bd1 (256) -> LN -> gelu -> @Wd2^T (128) -> gelu -> @Wd3^T (2)
  for (int o = wave; o < DM; o += 8) {
    const float2 w2 = *(const float2*)&Wd1[o * ED + lane * 2];
    const float2 z2 = *(const float2*)&obuf[384 + lane * 2];
    float s = wave_bsum(w2.x * z2.x + w2.y * z2.y);
    if (lane == 0) obuf[512 + o] = s + bd1[o];
  }
  __syncthreads();
  if (tid < 64) {
    float v0 = obuf[512 + lane], v1 = obuf[512 + lane + 64];
    float v2 = obuf[512 + lane + 128], v3 = obuf[512 + lane + 192];
    float m = wave_bsum(v0 + v1 + v2 + v3) * (1.0f / 256.0f);
    float d0 = v0 - m, d1 = v1 - m, d2 = v2 - m, d3 = v3 - m;
    float var = wave_bsum(d0 * d0 + d1 * d1 + d2 * d2 + d3 * d3) * (1.0f / 256.0f);
    float rstd = 1.0f / sqrtf(var + 1e-5f);
    obuf[512 + lane]       = gelu_f(d0 * rstd * lnd_g[lane]       + lnd_b[lane]);
    obuf[512 + lane + 64]  = gelu_f(d1 * rstd * lnd_g[lane + 64]  + lnd_b[lane + 64]);
    obuf[512 + lane + 128] = gelu_f(d2 * rstd * lnd_g[lane + 128] + lnd_b[lane + 128]);
    obuf[512 + lane + 192] = gelu_f(d3 * rstd * lnd_g[lane + 192] + lnd_b[lane + 192]);
  }
  __syncthreads();
  for (int o = wave; o < ED; o += 8) {
    const float4 w4 = *(const float4*)&Wd2[o * DM + lane * 4];
    const float4 g4 = *(const float4*)&obuf[512 + lane * 4];
    float s = wave_bsum(w4.x * g4.x + w4.y * g4.y + w4.z * g4.z + w4.w * g4.w);
    if (lane == 0) obuf[768 + o] = gelu_f(s + bd2[o]);
  }
  __syncthreads();
  if (wave < 2) {
    const float2 w2 = *(const float2*)&Wd3[wave * ED + lane * 2];
    const float2 g2 = *(const float2*)&obuf[768 + lane * 2];
    float s = wave_bsum(w2.x * g2.x + w2.y * g2.y);
    if (lane == 0) out[b * 2 + wave] = s + bd3[wave];
  }
}

__global__ void vqvae_finish(const float* __restrict__ ws, float* __restrict__ out) {
  __shared__ float red[256];
  int tid = threadIdx.x;
  float part = 0.f;
  for (int k = tid; k < KCB; k += 256) {
    float p = ws[1 + k] * (1.0f / 2048.0f);
    part += p * logf(p + 1e-10f);
  }
  red[tid] = part;
  __syncthreads();
  for (int s = 128; s > 0; s >>= 1) {
    if (tid < s) red[tid] += red[tid + s];
    __syncthreads();
  }
  if (tid == 0) {
    out[2 * NB + NB]     = 0.1f * ws[0] * (1.0f / (2048.0f * 128.0f));  // commitment loss
    out[2 * NB + NB + 1] = expf(-red[0]);                               // perplexity
  }
}

extern "C" void kernel_launch(void* const* d_in, const int* in_sizes, int n_in,
                              void* d_out, int out_size, void* d_ws, size_t ws_size,
                              hipStream_t stream) {
  (void)in_sizes; (void)n_in; (void)out_size; (void)ws_size;
  const float* x         = (const float*)d_in[0];
  const float* W_in      = (const float*)d_in[1];
  const float* b_in      = (const float*)d_in[2];
  const float* cls_token = (const float*)d_in[3];
  const float* Wqkv      = (const float*)d_in[4];
  const float* bqkv      = (const float*)d_in[5];
  const float* Wo        = (const float*)d_in[6];
  const float* bo        = (const float*)d_in[7];
  const float* W1        = (const float*)d_in[8];
  const float* b1        = (const float*)d_in[9];
  const float* W2        = (const float*)d_in[10];
  const float* b2        = (const float*)d_in[11];
  const float* ln1_g     = (const float*)d_in[12];
  const float* ln1_b     = (const float*)d_in[13];
  const float* ln2_g     = (const float*)d_in[14];
  const float* ln2_b     = (const float*)d_in[15];
  const float* lnf_g     = (const float*)d_in[16];
  const float* lnf_b     = (const float*)d_in[17];
  const float* W_out     = (const float*)d_in[18];
  const float* b_out     = (const float*)d_in[19];
  const float* codebook  = (const float*)d_in[20];
  const float* Wd1       = (const float*)d_in[21];
  const float* bd1       = (const float*)d_in[22];
  const float* lnd_g     = (const float*)d_in[23];
  const float* lnd_b     = (const float*)d_in[24];
  const float* Wd2       = (const float*)d_in[25];
  const float* bd2       = (const float*)d_in[26];
  const float* Wd3       = (const float*)d_in[27];
  const float* bd3       = (const float*)d_in[28];
  float* out = (float*)d_out;
  float* ws = (float*)d_ws;

  hipLaunchKernelGGL(vqvae_zero, dim3(5), dim3(256), 0, stream, ws);
  hipLaunchKernelGGL(vqvae_main, dim3(NB), dim3(NT), 0, stream,
                     x, W_in, b_in, cls_token, Wqkv, bqkv, Wo, bo, W1, b1, W2, b2,
                     ln1_g, ln1_b, ln2_g, ln2_b, lnf_g, lnf_b, W_out, b_out,
                     codebook, Wd1, bd1, lnd_g, lnd_b, Wd2, bd2, Wd3, bd3, out, ws);
  hipLaunchKernelGGL(vqvae_finish, dim3(1), dim3(256), 0, stream, ws, out);
}

// Round 7
// 28749.402 us; speedup vs baseline: 1.8486x; 1.2075x over previous
//
#include <hip/hip_runtime.h>
#include <math.h>

// Problem constants
#define NB   2048   // batch
#define SEQ  64
#define CIN  142
#define DM   256
#define NH   8
#define DHD  32
#define FFD  512
#define NL   3
#define ED   128
#define KCB  1024
#define TT   65     // SEQ+1 (cls prepended)
#define NT   512    // threads per block

__device__ __forceinline__ float gelu_f(float x) {
  return 0.5f * x * (1.0f + erff(x * 0.70710678118654752f));
}

__device__ __forceinline__ float wave_bsum(float v) {
#pragma unroll
  for (int off = 32; off >= 1; off >>= 1) v += __shfl_xor(v, off, 64);
  return v;
}
__device__ __forceinline__ float wave_bmax(float v) {
#pragma unroll
  for (int off = 32; off >= 1; off >>= 1) v = fmaxf(v, __shfl_xor(v, off, 64));
  return v;
}

// Register-tile GEMM: out[t][o] += sum_k src[t*sld+k] * Wg[grow(o)*wld + k]
// o = og + 32*oj (oj < OJN), t = tg + 16*i (t < TROWS). grow = rbase + (o&31) + rsel*(o>>5).
// Weights staged per 32-k chunk into Wst[row][36] (16B-aligned rows -> float4 LDS reads).
// SPILL MODEL (R1-R6): the staging phase is the register-pressure peak; with 8
// scalar loads in flight the allocator spills acc[5][4] across every chunk
// barrier (~68 B/thread/chunk -> tens of GB of HBM scratch). float4 staging
// (2 loads/thread, 1/4 the address regs) keeps the peak under the 128 cap.
// Callers must also keep NO extra register array live across a gemm_accum call.
template <int OJN, int TROWS>
__device__ __forceinline__ void gemm_accum(float acc[5][4],
                                           const float* __restrict__ Wg, int wld,
                                           int rbase, int rsel,
                                           const float* src, int sld, int kdim,
                                           float* Wst, int tid) {
  constexpr int IN = (TROWS + 15) / 16;
  const int og = tid & 31, tg = tid >> 5;
  constexpr int WROWS = 32 * OJN;
  const bool v4ok = ((wld & 3) == 0);  // wave-uniform; false only for embed (wld=142)
  for (int kc = 0; kc < kdim; kc += 32) {
    const int kw = (kdim - kc < 32) ? (kdim - kc) : 32;
    __syncthreads();  // protect Wst from previous consumers
    if (kw == 32 && v4ok) {
      // float4 staging: WROWS*8 float4s, 2 per thread (OJN=4) / 1.5 (OJN=3)
      for (int f = tid; f < WROWS * 8; f += NT) {
        int r = f >> 3, c4 = f & 7;
        int grow = rbase + (r & 31) + rsel * (r >> 5);
        const float4 w = *(const float4*)&Wg[grow * wld + kc + c4 * 4];
        *(float4*)&Wst[r * 36 + c4 * 4] = w;
      }
    } else if (kw == 32) {
      for (int f = tid; f < WROWS * 32; f += NT) {
        int r = f >> 5, c = f & 31;
        int grow = rbase + (r & 31) + rsel * (r >> 5);
        Wst[r * 36 + c] = Wg[grow * wld + kc + c];
      }
    } else {
      for (int f = tid; f < WROWS * kw; f += NT) {
        int r = f / kw, c = f - r * kw;
        int grow = rbase + (r & 31) + rsel * (r >> 5);
        Wst[r * 36 + c] = Wg[grow * wld + kc + c];
      }
    }
    __syncthreads();
    if (kw == 32) {
#pragma unroll
      for (int k = 0; k < 32; k += 4) {
        float4 wv[OJN];
#pragma unroll
        for (int oj = 0; oj < OJN; ++oj)
          wv[oj] = *(const float4*)&Wst[(og + 32 * oj) * 36 + k];
#pragma unroll
        for (int i = 0; i < IN; ++i) {
          int t = tg + 16 * i;
          if (i < IN - 1 || t < TROWS) {
            float4 hv = *(const float4*)&src[t * sld + kc + k];
#pragma unroll
            for (int oj = 0; oj < OJN; ++oj)
              acc[i][oj] += hv.x * wv[oj].x + hv.y * wv[oj].y +
                            hv.z * wv[oj].z + hv.w * wv[oj].w;
          }
        }
      }
    } else {  // tail (only embed: kw=14, even) - float2 path
      for (int k = 0; k < kw; k += 2) {
        float2 wv[OJN];
#pragma unroll
        for (int oj = 0; oj < OJN; ++oj)
          wv[oj] = *(const float2*)&Wst[(og + 32 * oj) * 36 + k];
#pragma unroll
        for (int i = 0; i < IN; ++i) {
          int t = tg + 16 * i;
          if (i < IN - 1 || t < TROWS) {
            float2 hv = *(const float2*)&src[t * sld + kc + k];
#pragma unroll
            for (int oj = 0; oj < OJN; ++oj)
              acc[i][oj] += hv.x * wv[oj].x + hv.y * wv[oj].y;
          }
        }
      }
    }
  }
}

__device__ __forceinline__ void ln_rows(float* buf, const float* g, const float* be,
                                        int wave, int lane) {
  for (int t = wave; t < TT; t += 8) {
    float v0 = buf[t * DM + lane],       v1 = buf[t * DM + lane + 64];
    float v2 = buf[t * DM + lane + 128], v3 = buf[t * DM + lane + 192];
    float m = wave_bsum(v0 + v1 + v2 + v3) * (1.0f / 256.0f);
    float d0 = v0 - m, d1 = v1 - m, d2 = v2 - m, d3 = v3 - m;
    float var = wave_bsum(d0 * d0 + d1 * d1 + d2 * d2 + d3 * d3) * (1.0f / 256.0f);
    float rstd = 1.0f / sqrtf(var + 1e-5f);
    buf[t * DM + lane]       = d0 * rstd * g[lane]       + be[lane];
    buf[t * DM + lane + 64]  = d1 * rstd * g[lane + 64]  + be[lane + 64];
    buf[t * DM + lane + 128] = d2 * rstd * g[lane + 128] + be[lane + 128];
    buf[t * DM + lane + 192] = d3 * rstd * g[lane + 192] + be[lane + 192];
  }
}

__global__ void vqvae_zero(float* __restrict__ ws) {
  int i = blockIdx.x * blockDim.x + threadIdx.x;
  if (i < 1025) ws[i] = 0.f;
}

// LDS (161,216 B) limits to 1 block/CU = 8 waves = 2 waves/SIMD.
__global__ __attribute__((amdgpu_flat_work_group_size(512, 512), amdgpu_waves_per_eu(2)))
void vqvae_main(
    const float* __restrict__ x, const float* __restrict__ W_in,
    const float* __restrict__ b_in, const float* __restrict__ cls_token,
    const float* __restrict__ Wqkv, const float* __restrict__ bqkv,
    const float* __restrict__ Wo, const float* __restrict__ bo,
    const float* __restrict__ W1, const float* __restrict__ b1,
    const float* __restrict__ W2, const float* __restrict__ b2,
    const float* __restrict__ ln1_g, const float* __restrict__ ln1_b,
    const float* __restrict__ ln2_g, const float* __restrict__ ln2_b,
    const float* __restrict__ lnf_g, const float* __restrict__ lnf_b,
    const float* __restrict__ W_out, const float* __restrict__ b_out,
    const float* __restrict__ codebook, const float* __restrict__ Wd1,
    const float* __restrict__ bd1, const float* __restrict__ lnd_g,
    const float* __restrict__ lnd_b, const float* __restrict__ Wd2,
    const float* __restrict__ bd2, const float* __restrict__ Wd3,
    const float* __restrict__ bd3, float* __restrict__ out,
    float* __restrict__ ws) {
  // 161,216 B static LDS (gfx950: 163,840 B available)
  __shared__ __align__(16) float hbuf[TT * DM];  // residual stream; later: codebook chunk [128][129]
  __shared__ __align__(16) float obuf[16896];    // x-stage / attn-out / FF f1 [<=33][512] / head scalars
  __shared__ __align__(16) float scr[6768];      // Wstage [<=128][36] | qkv col-major [96][65] + p rows

  const int tid = threadIdx.x;
  const int b = blockIdx.x;
  const int lane = tid & 63, wave = tid >> 6;
  const int og = tid & 31, tg = tid >> 5;

  // ---------------- embed: h[0]=cls, h[1+r] = x[r] @ W_in^T + b_in + PE[r] ----------------
  for (int f = tid; f < SEQ * CIN; f += NT) {  // stage x[b] into obuf, rows padded to 144
    int r = f / CIN, c = f - r * CIN;
    obuf[r * 144 + c] = x[(size_t)b * (SEQ * CIN) + f];
  }
  if (tid < DM) hbuf[tid] = cls_token[tid];
  __syncthreads();

  for (int oc = 0; oc < 2; ++oc) {
    float acc[5][4] = {{0.f}};
    gemm_accum<4, 64>(acc, W_in, CIN, oc * 128, 32, obuf, 144, CIN, scr, tid);
#pragma unroll
    for (int i = 0; i < 4; ++i) {
      int r = tg + 16 * i;
#pragma unroll
      for (int oj = 0; oj < 4; ++oj) {
        int d = oc * 128 + og + 32 * oj;
        float div = expf(-(float)(d & ~1) * (9.210340371976184f / 256.0f));
        float ang = (float)r * div;
        float pe = (d & 1) ? cosf(ang) : sinf(ang);
        hbuf[(r + 1) * DM + d] = acc[i][oj] + b_in[d] + pe;
      }
    }
  }
  __syncthreads();

  // ---------------- transformer layers ----------------
  for (int li = 0; li < NL; ++li) {
    const float* Wqkv_l = Wqkv + (size_t)li * 768 * DM;
    const float* bqkv_l = bqkv + li * 768;
    const float* Wo_l = Wo + (size_t)li * DM * DM;
    const float* bo_l = bo + li * DM;
    const float* W1_l = W1 + (size_t)li * FFD * DM;
    const float* b1_l = b1 + li * FFD;
    const float* W2_l = W2 + (size_t)li * DM * FFD;
    const float* b2_l = b2 + li * DM;

    // ---- attention (per head): qkv GEMM -> col-major scr, online softmax, o -> obuf ----
    for (int hd = 0; hd < NH; ++hd) {
      float acc[5][4] = {{0.f}};
      // rows: q=hd*32+og (oj=0), k=256+hd*32+og (oj=1), v=512+hd*32+og (oj=2)
      gemm_accum<3, 65>(acc, Wqkv_l, DM, hd * 32, 256, hbuf, DM, DM, scr, tid);
      __syncthreads();  // all Wst reads done before qkv overwrites scr
#pragma unroll
      for (int i = 0; i < 5; ++i) {
        int t = tg + 16 * i;
        if (t < TT) {
#pragma unroll
          for (int oj = 0; oj < 3; ++oj)
            scr[(og + 32 * oj) * TT + t] = acc[i][oj] + bqkv_l[oj * 256 + hd * 32 + og];
        }
      }
      __syncthreads();

      // scores: lane=u(0..63), rows t = wave+8*it; u=64 handled via reduced partial
      float sv[9];
#pragma unroll
      for (int it = 0; it < 9; ++it) sv[it] = 0.f;
#pragma unroll 4
      for (int j = 0; j < 32; ++j) {
        float kv = scr[(32 + j) * TT + lane];  // k[lane][j]
#pragma unroll
        for (int it = 0; it < 9; ++it) {
          int t = wave + 8 * it;
          if (it < 8 || t < TT) sv[it] += scr[j * TT + t] * kv;  // q[t][j] broadcast
        }
      }
#pragma unroll
      for (int it = 0; it < 9; ++it) {
        int t = wave + 8 * it;
        if (t < TT) {  // wave-uniform guard
          int jj = lane & 31;
          float p64 = scr[jj * TT + t] * scr[(32 + jj) * TT + 64] * 0.5f;  // halves dup -> *0.5
          p64 = wave_bsum(p64);
          const float sc = 0.17677669529663687f;  // 1/sqrt(32)
          float s = sv[it] * sc, s64 = p64 * sc;
          float m = fmaxf(wave_bmax(s), s64);
          float e = expf(s - m), e64 = expf(s64 - m);
          float inv = 1.0f / (wave_bsum(e) + e64);
          float* prow = &scr[96 * TT + wave * 66];
          prow[lane] = e * inv;
          if (lane == 0) prow[64] = e64 * inv;
          // o[t][e] = sum_u p[u] * v[u][e]; lanes (e, u-half)
          int e_ = lane & 31, half = lane >> 5;
          float o = 0.f;
          int u0 = half * 33, u1 = half ? 65 : 33;
#pragma unroll 4
          for (int u = u0; u < u1; ++u) o += prow[u] * scr[(64 + e_) * TT + u];
          o += __shfl_down(o, 32, 64);
          if (lane < 32) obuf[t * DM + hd * 32 + e_] = o;
        }
      }
      __syncthreads();  // before next head re-stages scr
    }

    // ---- proj + residual: h += o @ Wo^T + bo ; LN1 ----
    for (int oc = 0; oc < 2; ++oc) {
      float acc[5][4] = {{0.f}};
      gemm_accum<4, 65>(acc, Wo_l, DM, oc * 128, 32, obuf, DM, DM, scr, tid);
#pragma unroll
      for (int i = 0; i < 5; ++i) {
        int t = tg + 16 * i;
        if (t < TT) {
#pragma unroll
          for (int oj = 0; oj < 4; ++oj) {
            int d = oc * 128 + og + 32 * oj;
            hbuf[t * DM + d] += acc[i][oj] + bo_l[d];
          }
        }
      }
    }
    __syncthreads();
    ln_rows(hbuf, ln1_g + li * DM, ln1_b + li * DM, wave, lane);
    __syncthreads();

    // ---- FF: T-split two-pass; ZERO registers live across any gemm ----
    // pass 0: rows [0,32). pass 1: rows [32,65).
    // f1 (full 512 hidden cols) for the pass lives in obuf [nr][512].
    // W2 then runs one K=512 sweep per 128-col output chunk, writing
    // ff + u + b2 directly into hbuf rows of this pass (disjoint from the
    // u rows the other pass's W1 still needs).
    for (int ps = 0; ps < 2; ++ps) {
      const int r0 = ps ? 32 : 0;
      const int nr = ps ? 33 : 32;
      for (int mc = 0; mc < 4; ++mc) {
        float acc[5][4] = {{0.f}};
        if (ps == 0)
          gemm_accum<4, 32>(acc, W1_l, DM, mc * 128, 32, hbuf + r0 * DM, DM, DM, scr, tid);
        else
          gemm_accum<4, 33>(acc, W1_l, DM, mc * 128, 32, hbuf + r0 * DM, DM, DM, scr, tid);
#pragma unroll
        for (int i = 0; i < 3; ++i) {
          int t = tg + 16 * i;
          if (t < nr) {
#pragma unroll
            for (int oj = 0; oj < 4; ++oj) {
              int m = mc * 128 + og + 32 * oj;
              obuf[t * FFD + m] = gelu_f(acc[i][oj] + b1_l[m]);
            }
          }
        }
      }
      for (int oc = 0; oc < 2; ++oc) {
        float acc[5][4] = {{0.f}};
        if (ps == 0)
          gemm_accum<4, 32>(acc, W2_l, FFD, oc * 128, 32, obuf, FFD, FFD, scr, tid);
        else
          gemm_accum<4, 33>(acc, W2_l, FFD, oc * 128, 32, obuf, FFD, FFD, scr, tid);
#pragma unroll
        for (int i = 0; i < 3; ++i) {
          int t = tg + 16 * i;
          if (t < nr) {
#pragma unroll
            for (int oj = 0; oj < 4; ++oj) {
              int d = oc * 128 + og + 32 * oj;
              int gi = (r0 + t) * DM + d;
              hbuf[gi] = hbuf[gi] + acc[i][oj] + b2_l[d];  // own element, no race
            }
          }
        }
      }
    }
    __syncthreads();
    ln_rows(hbuf, ln2_g + li * DM, ln2_b + li * DM, wave, lane);
    __syncthreads();
  }

  // ---------------- head: lnf(cls) -> z_e -> VQ argmin -> decoder ----------------
  if (tid < 64) {  // lnf on row 0 -> obuf[0..255]
    float v0 = hbuf[lane], v1 = hbuf[lane + 64], v2 = hbuf[lane + 128], v3 = hbuf[lane + 192];
    float m = wave_bsum(v0 + v1 + v2 + v3) * (1.0f / 256.0f);
    float d0 = v0 - m, d1 = v1 - m, d2 = v2 - m, d3 = v3 - m;
    float var = wave_bsum(d0 * d0 + d1 * d1 + d2 * d2 + d3 * d3) * (1.0f / 256.0f);
    float rstd = 1.0f / sqrtf(var + 1e-5f);
    obuf[lane]       = d0 * rstd * lnf_g[lane]       + lnf_b[lane];
    obuf[lane + 64]  = d1 * rstd * lnf_g[lane + 64]  + lnf_b[lane + 64];
    obuf[lane + 128] = d2 * rstd * lnf_g[lane + 128] + lnf_b[lane + 128];
    obuf[lane + 192] = d3 * rstd * lnf_g[lane + 192] + lnf_b[lane + 192];
  }
  __syncthreads();
  // z_e = lnf(cls) @ W_out^T + b_out -> obuf[256..384)
  for (int o = wave; o < ED; o += 8) {
    const float4 w4 = *(const float4*)&W_out[o * DM + lane * 4];
    const float4 c4 = *(const float4*)&obuf[lane * 4];
    float s = w4.x * c4.x + w4.y * c4.y + w4.z * c4.z + w4.w * c4.w;
    s = wave_bsum(s);
    if (lane == 0) obuf[256 + o] = s + b_out[o];
  }
  __syncthreads();

  // VQ argmin over |cb|^2 - 2 ze.cb (|ze|^2 constant); first-index tie-break
  float bestv = 3.4e38f;
  int bestk = 0;
  for (int ch = 0; ch < 8; ++ch) {
    __syncthreads();
    for (int f = tid; f < 128 * 128; f += NT) {  // stage cb chunk, rows padded to 129
      int r = f >> 7, c = f & 127;
      hbuf[r * 129 + c] = codebook[(size_t)(ch * 128 + r) * ED + c];
    }
    __syncthreads();
    {
      int kl = tid & 127, q = tid >> 7;
      float part = 0.f;
#pragma unroll 8
      for (int jj = 0; jj < 32; ++jj) {
        int e = q * 32 + jj;
        float cv = hbuf[kl * 129 + e];
        part += cv * (cv - 2.0f * obuf[256 + e]);
      }
      scr[kl * 4 + q] = part;
    }
    __syncthreads();
    if (tid < 128) {
      float d2v = scr[tid * 4] + scr[tid * 4 + 1] + scr[tid * 4 + 2] + scr[tid * 4 + 3];
      int kk = ch * 128 + tid;
      if (d2v < bestv) { bestv = d2v; bestk = kk; }  // ascending k per thread
    }
  }
  if (tid < 128) {
    scr[512 + tid] = bestv;
    scr[640 + tid] = __int_as_float(bestk);
  }
  __syncthreads();
  if (tid == 0) {
    float bv = 3.4e38f;
    int bk = 1 << 30;
    for (int j = 0; j < 128; ++j) {
      float v = scr[512 + j];
      int kk = __float_as_int(scr[640 + j]);
      if (v < bv || (v == bv && kk < bk)) { bv = v; bk = kk; }
    }
    scr[700] = __int_as_float(bk);
    out[2 * NB + b] = (float)bk;  // indices output (as float value)
  }
  __syncthreads();
  const int bk = __float_as_int(scr[700]);

  // z_q -> obuf[384..512); commitment + histogram
  if (tid < ED) {
    float zqv = codebook[(size_t)bk * ED + tid];
    obuf[384 + tid] = zqv;
    float df = zqv - obuf[256 + tid];
    float sq = wave_bsum(df * df);
    if ((tid & 63) == 0) atomicAdd(&ws[0], sq);
  }
  if (tid == 0) atomicAdd(&ws[1 + bk], 1.0f);
  __syncthreads();

  // decoder: d1 = zq @ Wd1^T + bd1 (256) -> LN -> gelu -> @Wd2^T (128) -> gelu -> @Wd3^T (2)
  for (int o = wave; o < DM; o += 8) {
    const float2 w2 = *(const float2*)&Wd1[o * ED + lane * 2];
    const float2 z2 = *(const float2*)&obuf[384 + lane * 2];
    float s = wave_bsum(w2.x * z2.x + w2.y * z2.y);
    if (lane == 0) obuf[512 + o] = s + bd1[o];
  }
  __syncthreads();
  if (tid < 64) {
    float v0 = obuf[512 + lane], v1 = obuf[512 + lane + 64];
    float v2 = obuf[512 + lane + 128], v3 = obuf[512 + lane + 192];
    float m = wave_bsum(v0 + v1 + v2 + v3) * (1.0f / 256.0f);
    float d0 = v0 - m, d1 = v1 - m, d2 = v2 - m, d3 = v3 - m;
    float var = wave_bsum(d0 * d0 + d1 * d1 + d2 * d2 + d3 * d3) * (1.0f / 256.0f);
    float rstd = 1.0f / sqrtf(var + 1e-5f);
    obuf[512 + lane]       = gelu_f(d0 * rstd * lnd_g[lane]       + lnd_b[lane]);
    obuf[512 + lane + 64]  = gelu_f(d1 * rstd * lnd_g[lane + 64]  + lnd_b[lane + 64]);
    obuf[512 + lane + 128] = gelu_f(d2 * rstd * lnd_g[lane + 128] + lnd_b[lane + 128]);
    obuf[512 + lane + 192] = gelu_f(d3 * rstd * lnd_g[lane + 192] + lnd_b[lane + 192]);
  }
  __syncthreads();
  for (int o = wave; o < ED; o += 8) {
    const float4 w4 = *(const float4*)&Wd2[o * DM + lane * 4];
    const float4 g4 = *(const float4*)&obuf[512 + lane * 4];
    float s = wave_bsum(w4.x * g4.x + w4.y * g4.y + w4.z * g4.z + w4.w * g4.w);
    if (lane == 0) obuf[768 + o] = gelu_f(s + bd2[o]);
  }
  __syncthreads();
  if (wave < 2) {
    const float2 w2 = *(const float2*)&Wd3[wave * ED + lane * 2];
    const float2 g2 = *(const float2*)&obuf[768 + lane * 2];
    float s = wave_bsum(w2.x * g2.x + w2.y * g2.y);
    if (lane == 0) out[b * 2 + wave] = s + bd3[wave];
  }
}

__global__ void vqvae_finish(const float* __restrict__ ws, float* __restrict__ out) {
  __shared__ float red[256];
  int tid = threadIdx.x;
  float part = 0.f;
  for (int k = tid; k < KCB; k += 256) {
    float p = ws[1 + k] * (1.0f / 2048.0f);
    part += p * logf(p + 1e-10f);
  }
  red[tid] = part;
  __syncthreads();
  for (int s = 128; s > 0; s >>= 1) {
    if (tid < s) red[tid] += red[tid + s];
    __syncthreads();
  }
  if (tid == 0) {
    out[2 * NB + NB]     = 0.1f * ws[0] * (1.0f / (2048.0f * 128.0f));  // commitment loss
    out[2 * NB + NB + 1] = expf(-red[0]);                               // perplexity
  }
}

extern "C" void kernel_launch(void* const* d_in, const int* in_sizes, int n_in,
                              void* d_out, int out_size, void* d_ws, size_t ws_size,
                              hipStream_t stream) {
  (void)in_sizes; (void)n_in; (void)out_size; (void)ws_size;
  const float* x         = (const float*)d_in[0];
  const float* W_in      = (const float*)d_in[1];
  const float* b_in      = (const float*)d_in[2];
  const float* cls_token = (const float*)d_in[3];
  const float* Wqkv      = (const float*)d_in[4];
  const float* bqkv      = (const float*)d_in[5];
  const float* Wo        = (const float*)d_in[6];
  const float* bo        = (const float*)d_in[7];
  const float* W1        = (const float*)d_in[8];
  const float* b1        = (const float*)d_in[9];
  const float* W2        = (const float*)d_in[10];
  const float* b2        = (const float*)d_in[11];
  const float* ln1_g     = (const float*)d_in[12];
  const float* ln1_b     = (const float*)d_in[13];
  const float* ln2_g     = (const float*)d_in[14];
  const float* ln2_b     = (const float*)d_in[15];
  const float* lnf_g     = (const float*)d_in[16];
  const float* lnf_b     = (const float*)d_in[17];
  const float* W_out     = (const float*)d_in[18];
  const float* b_out     = (const float*)d_in[19];
  const float* codebook  = (const float*)d_in[20];
  const float* Wd1       = (const float*)d_in[21];
  const float* bd1       = (const float*)d_in[22];
  const float* lnd_g     = (const float*)d_in[23];
  const float* lnd_b     = (const float*)d_in[24];
  const float* Wd2       = (const float*)d_in[25];
  const float* bd2       = (const float*)d_in[26];
  const float* Wd3       = (const float*)d_in[27];
  const float* bd3       = (const float*)d_in[28];
  float* out = (float*)d_out;
  float* ws = (float*)d_ws;

  hipLaunchKernelGGL(vqvae_zero, dim3(5), dim3(256), 0, stream, ws);
  hipLaunchKernelGGL(vqvae_main, dim3(NB), dim3(NT), 0, stream,
                     x, W_in, b_in, cls_token, Wqkv, bqkv, Wo, bo, W1, b1, W2, b2,
                     ln1_g, ln1_b, ln2_g, ln2_b, lnf_g, lnf_b, W_out, b_out,
                     codebook, Wd1, bd1, lnd_g, lnd_b, Wd2, bd2, Wd3, bd3, out, ws);
  hipLaunchKernelGGL(vqvae_finish, dim3(1), dim3(256), 0, stream, ws, out);
}

// Round 8
// 17052.771 us; speedup vs baseline: 3.1166x; 1.6859x over previous
//
#include <hip/hip_runtime.h>
#include <math.h>

// Problem constants
#define NB   2048   // batch
#define SEQ  64
#define CIN  142
#define DM   256
#define NH   8
#define DHD  32
#define FFD  512
#define NL   3
#define ED   128
#define KCB  1024
#define TT   65     // SEQ+1 (cls prepended)
#define NT   512    // threads per block

__device__ __forceinline__ float gelu_f(float x) {
  return 0.5f * x * (1.0f + erff(x * 0.70710678118654752f));
}

__device__ __forceinline__ float wave_bsum(float v) {
#pragma unroll
  for (int off = 32; off >= 1; off >>= 1) v += __shfl_xor(v, off, 64);
  return v;
}
__device__ __forceinline__ float wave_bmax(float v) {
#pragma unroll
  for (int off = 32; off >= 1; off >>= 1) v = fmaxf(v, __shfl_xor(v, off, 64));
  return v;
}

// Register-tile GEMM: out[t][o] += sum_k src[t*sld+k] * Wg[grow(o)*wld + k]
// o = og + 32*oj (oj < OJN), t = tg + 16*i (t < TROWS). grow = rbase + (o&31) + rsel*(o>>5).
// Weights staged per 32-k chunk into Wst[row][36] (16B-aligned rows -> float4 LDS reads).
// SPILL MODEL (R1-R7): full unroll of the k-loop lets the pre-RA scheduler hoist
// ~8 iterations of wv/hv LDS loads (~280 regs in flight); the allocator (128-VGPR
// cap, attributes to raise it are ignored) then spills acc every chunk
// (~68 B/thread/chunk -> tens of GB HBM scratch). "#pragma unroll 2" caps the
// in-flight set at ~107 regs. Callers must also keep NO extra register array
// live across a gemm_accum call.
template <int OJN, int TROWS>
__device__ __forceinline__ void gemm_accum(float acc[5][4],
                                           const float* __restrict__ Wg, int wld,
                                           int rbase, int rsel,
                                           const float* src, int sld, int kdim,
                                           float* Wst, int tid) {
  constexpr int IN = (TROWS + 15) / 16;
  const int og = tid & 31, tg = tid >> 5;
  constexpr int WROWS = 32 * OJN;
  const bool v4ok = ((wld & 3) == 0);  // wave-uniform; false only for embed (wld=142)
  for (int kc = 0; kc < kdim; kc += 32) {
    const int kw = (kdim - kc < 32) ? (kdim - kc) : 32;
    __syncthreads();  // protect Wst from previous consumers
    if (kw == 32 && v4ok) {
      // float4 staging: WROWS*8 float4s, 2 per thread (OJN=4) / 1.5 (OJN=3)
      for (int f = tid; f < WROWS * 8; f += NT) {
        int r = f >> 3, c4 = f & 7;
        int grow = rbase + (r & 31) + rsel * (r >> 5);
        const float4 w = *(const float4*)&Wg[grow * wld + kc + c4 * 4];
        *(float4*)&Wst[r * 36 + c4 * 4] = w;
      }
    } else if (kw == 32) {
      for (int f = tid; f < WROWS * 32; f += NT) {
        int r = f >> 5, c = f & 31;
        int grow = rbase + (r & 31) + rsel * (r >> 5);
        Wst[r * 36 + c] = Wg[grow * wld + kc + c];
      }
    } else {
      for (int f = tid; f < WROWS * kw; f += NT) {
        int r = f / kw, c = f - r * kw;
        int grow = rbase + (r & 31) + rsel * (r >> 5);
        Wst[r * 36 + c] = Wg[grow * wld + kc + c];
      }
    }
    __syncthreads();
    if (kw == 32) {
#pragma unroll 2
      for (int k = 0; k < 32; k += 4) {
        float4 wv[OJN];
#pragma unroll
        for (int oj = 0; oj < OJN; ++oj)
          wv[oj] = *(const float4*)&Wst[(og + 32 * oj) * 36 + k];
#pragma unroll
        for (int i = 0; i < IN; ++i) {
          int t = tg + 16 * i;
          if (i < IN - 1 || t < TROWS) {
            float4 hv = *(const float4*)&src[t * sld + kc + k];
#pragma unroll
            for (int oj = 0; oj < OJN; ++oj)
              acc[i][oj] += hv.x * wv[oj].x + hv.y * wv[oj].y +
                            hv.z * wv[oj].z + hv.w * wv[oj].w;
          }
        }
      }
    } else {  // tail (only embed: kw=14, even) - float2 path
#pragma unroll 2
      for (int k = 0; k < kw; k += 2) {
        float2 wv[OJN];
#pragma unroll
        for (int oj = 0; oj < OJN; ++oj)
          wv[oj] = *(const float2*)&Wst[(og + 32 * oj) * 36 + k];
#pragma unroll
        for (int i = 0; i < IN; ++i) {
          int t = tg + 16 * i;
          if (i < IN - 1 || t < TROWS) {
            float2 hv = *(const float2*)&src[t * sld + kc + k];
#pragma unroll
            for (int oj = 0; oj < OJN; ++oj)
              acc[i][oj] += hv.x * wv[oj].x + hv.y * wv[oj].y;
          }
        }
      }
    }
  }
}

__device__ __forceinline__ void ln_rows(float* buf, const float* g, const float* be,
                                        int wave, int lane) {
  for (int t = wave; t < TT; t += 8) {
    float v0 = buf[t * DM + lane],       v1 = buf[t * DM + lane + 64];
    float v2 = buf[t * DM + lane + 128], v3 = buf[t * DM + lane + 192];
    float m = wave_bsum(v0 + v1 + v2 + v3) * (1.0f / 256.0f);
    float d0 = v0 - m, d1 = v1 - m, d2 = v2 - m, d3 = v3 - m;
    float var = wave_bsum(d0 * d0 + d1 * d1 + d2 * d2 + d3 * d3) * (1.0f / 256.0f);
    float rstd = 1.0f / sqrtf(var + 1e-5f);
    buf[t * DM + lane]       = d0 * rstd * g[lane]       + be[lane];
    buf[t * DM + lane + 64]  = d1 * rstd * g[lane + 64]  + be[lane + 64];
    buf[t * DM + lane + 128] = d2 * rstd * g[lane + 128] + be[lane + 128];
    buf[t * DM + lane + 192] = d3 * rstd * g[lane + 192] + be[lane + 192];
  }
}

__global__ void vqvae_zero(float* __restrict__ ws) {
  int i = blockIdx.x * blockDim.x + threadIdx.x;
  if (i < 1025) ws[i] = 0.f;
}

// LDS (161,216 B) limits to 1 block/CU = 8 waves = 2 waves/SIMD.
__global__ __attribute__((amdgpu_flat_work_group_size(512, 512), amdgpu_waves_per_eu(2)))
void vqvae_main(
    const float* __restrict__ x, const float* __restrict__ W_in,
    const float* __restrict__ b_in, const float* __restrict__ cls_token,
    const float* __restrict__ Wqkv, const float* __restrict__ bqkv,
    const float* __restrict__ Wo, const float* __restrict__ bo,
    const float* __restrict__ W1, const float* __restrict__ b1,
    const float* __restrict__ W2, const float* __restrict__ b2,
    const float* __restrict__ ln1_g, const float* __restrict__ ln1_b,
    const float* __restrict__ ln2_g, const float* __restrict__ ln2_b,
    const float* __restrict__ lnf_g, const float* __restrict__ lnf_b,
    const float* __restrict__ W_out, const float* __restrict__ b_out,
    const float* __restrict__ codebook, const float* __restrict__ Wd1,
    const float* __restrict__ bd1, const float* __restrict__ lnd_g,
    const float* __restrict__ lnd_b, const float* __restrict__ Wd2,
    const float* __restrict__ bd2, const float* __restrict__ Wd3,
    const float* __restrict__ bd3, float* __restrict__ out,
    float* __restrict__ ws) {
  // 161,216 B static LDS (gfx950: 163,840 B available)
  __shared__ __align__(16) float hbuf[TT * DM];  // residual stream; later: codebook chunk [128][129]
  __shared__ __align__(16) float obuf[16896];    // x-stage / attn-out / FF f1 [<=33][512] / head scalars
  __shared__ __align__(16) float scr[6768];      // Wstage [<=128][36] | qkv col-major [96][65] + p rows

  const int tid = threadIdx.x;
  const int b = blockIdx.x;
  const int lane = tid & 63, wave = tid >> 6;
  const int og = tid & 31, tg = tid >> 5;

  // ---------------- embed: h[0]=cls, h[1+r] = x[r] @ W_in^T + b_in + PE[r] ----------------
  for (int f = tid; f < SEQ * CIN; f += NT) {  // stage x[b] into obuf, rows padded to 144
    int r = f / CIN, c = f - r * CIN;
    obuf[r * 144 + c] = x[(size_t)b * (SEQ * CIN) + f];
  }
  if (tid < DM) hbuf[tid] = cls_token[tid];
  __syncthreads();

  for (int oc = 0; oc < 2; ++oc) {
    float acc[5][4] = {{0.f}};
    gemm_accum<4, 64>(acc, W_in, CIN, oc * 128, 32, obuf, 144, CIN, scr, tid);
#pragma unroll
    for (int i = 0; i < 4; ++i) {
      int r = tg + 16 * i;
#pragma unroll
      for (int oj = 0; oj < 4; ++oj) {
        int d = oc * 128 + og + 32 * oj;
        float div = expf(-(float)(d & ~1) * (9.210340371976184f / 256.0f));
        float ang = (float)r * div;
        float pe = (d & 1) ? cosf(ang) : sinf(ang);
        hbuf[(r + 1) * DM + d] = acc[i][oj] + b_in[d] + pe;
      }
    }
  }
  __syncthreads();

  // ---------------- transformer layers ----------------
  for (int li = 0; li < NL; ++li) {
    const float* Wqkv_l = Wqkv + (size_t)li * 768 * DM;
    const float* bqkv_l = bqkv + li * 768;
    const float* Wo_l = Wo + (size_t)li * DM * DM;
    const float* bo_l = bo + li * DM;
    const float* W1_l = W1 + (size_t)li * FFD * DM;
    const float* b1_l = b1 + li * FFD;
    const float* W2_l = W2 + (size_t)li * DM * FFD;
    const float* b2_l = b2 + li * DM;

    // ---- attention (per head): qkv GEMM -> col-major scr, online softmax, o -> obuf ----
    for (int hd = 0; hd < NH; ++hd) {
      float acc[5][4] = {{0.f}};
      // rows: q=hd*32+og (oj=0), k=256+hd*32+og (oj=1), v=512+hd*32+og (oj=2)
      gemm_accum<3, 65>(acc, Wqkv_l, DM, hd * 32, 256, hbuf, DM, DM, scr, tid);
      __syncthreads();  // all Wst reads done before qkv overwrites scr
#pragma unroll
      for (int i = 0; i < 5; ++i) {
        int t = tg + 16 * i;
        if (t < TT) {
#pragma unroll
          for (int oj = 0; oj < 3; ++oj)
            scr[(og + 32 * oj) * TT + t] = acc[i][oj] + bqkv_l[oj * 256 + hd * 32 + og];
        }
      }
      __syncthreads();

      // scores: lane=u(0..63), rows t = wave+8*it; u=64 handled via reduced partial
      float sv[9];
#pragma unroll
      for (int it = 0; it < 9; ++it) sv[it] = 0.f;
#pragma unroll 4
      for (int j = 0; j < 32; ++j) {
        float kv = scr[(32 + j) * TT + lane];  // k[lane][j]
#pragma unroll
        for (int it = 0; it < 9; ++it) {
          int t = wave + 8 * it;
          if (it < 8 || t < TT) sv[it] += scr[j * TT + t] * kv;  // q[t][j] broadcast
        }
      }
#pragma unroll
      for (int it = 0; it < 9; ++it) {
        int t = wave + 8 * it;
        if (t < TT) {  // wave-uniform guard
          int jj = lane & 31;
          float p64 = scr[jj * TT + t] * scr[(32 + jj) * TT + 64] * 0.5f;  // halves dup -> *0.5
          p64 = wave_bsum(p64);
          const float sc = 0.17677669529663687f;  // 1/sqrt(32)
          float s = sv[it] * sc, s64 = p64 * sc;
          float m = fmaxf(wave_bmax(s), s64);
          float e = expf(s - m), e64 = expf(s64 - m);
          float inv = 1.0f / (wave_bsum(e) + e64);
          float* prow = &scr[96 * TT + wave * 66];
          prow[lane] = e * inv;
          if (lane == 0) prow[64] = e64 * inv;
          // o[t][e] = sum_u p[u] * v[u][e]; lanes (e, u-half)
          int e_ = lane & 31, half = lane >> 5;
          float o = 0.f;
          int u0 = half * 33, u1 = half ? 65 : 33;
#pragma unroll 4
          for (int u = u0; u < u1; ++u) o += prow[u] * scr[(64 + e_) * TT + u];
          o += __shfl_down(o, 32, 64);
          if (lane < 32) obuf[t * DM + hd * 32 + e_] = o;
        }
      }
      __syncthreads();  // before next head re-stages scr
    }

    // ---- proj + residual: h += o @ Wo^T + bo ; LN1 ----
    for (int oc = 0; oc < 2; ++oc) {
      float acc[5][4] = {{0.f}};
      gemm_accum<4, 65>(acc, Wo_l, DM, oc * 128, 32, obuf, DM, DM, scr, tid);
#pragma unroll
      for (int i = 0; i < 5; ++i) {
        int t = tg + 16 * i;
        if (t < TT) {
#pragma unroll
          for (int oj = 0; oj < 4; ++oj) {
            int d = oc * 128 + og + 32 * oj;
            hbuf[t * DM + d] += acc[i][oj] + bo_l[d];
          }
        }
      }
    }
    __syncthreads();
    ln_rows(hbuf, ln1_g + li * DM, ln1_b + li * DM, wave, lane);
    __syncthreads();

    // ---- FF: T-split two-pass; ZERO registers live across any gemm ----
    // pass 0: rows [0,32). pass 1: rows [32,65).
    // f1 (full 512 hidden cols) for the pass lives in obuf [nr][512].
    // W2 then runs one K=512 sweep per 128-col output chunk, writing
    // ff + u + b2 directly into hbuf rows of this pass (disjoint from the
    // u rows the other pass's W1 still needs).
    for (int ps = 0; ps < 2; ++ps) {
      const int r0 = ps ? 32 : 0;
      const int nr = ps ? 33 : 32;
      for (int mc = 0; mc < 4; ++mc) {
        float acc[5][4] = {{0.f}};
        if (ps == 0)
          gemm_accum<4, 32>(acc, W1_l, DM, mc * 128, 32, hbuf + r0 * DM, DM, DM, scr, tid);
        else
          gemm_accum<4, 33>(acc, W1_l, DM, mc * 128, 32, hbuf + r0 * DM, DM, DM, scr, tid);
#pragma unroll
        for (int i = 0; i < 3; ++i) {
          int t = tg + 16 * i;
          if (t < nr) {
#pragma unroll
            for (int oj = 0; oj < 4; ++oj) {
              int m = mc * 128 + og + 32 * oj;
              obuf[t * FFD + m] = gelu_f(acc[i][oj] + b1_l[m]);
            }
          }
        }
      }
      for (int oc = 0; oc < 2; ++oc) {
        float acc[5][4] = {{0.f}};
        if (ps == 0)
          gemm_accum<4, 32>(acc, W2_l, FFD, oc * 128, 32, obuf, FFD, FFD, scr, tid);
        else
          gemm_accum<4, 33>(acc, W2_l, FFD, oc * 128, 32, obuf, FFD, FFD, scr, tid);
#pragma unroll
        for (int i = 0; i < 3; ++i) {
          int t = tg + 16 * i;
          if (t < nr) {
#pragma unroll
            for (int oj = 0; oj < 4; ++oj) {
              int d = oc * 128 + og + 32 * oj;
              int gi = (r0 + t) * DM + d;
              hbuf[gi] = hbuf[gi] + acc[i][oj] + b2_l[d];  // own element, no race
            }
          }
        }
      }
    }
    __syncthreads();
    ln_rows(hbuf, ln2_g + li * DM, ln2_b + li * DM, wave, lane);
    __syncthreads();
  }

  // ---------------- head: lnf(cls) -> z_e -> VQ argmin -> decoder ----------------
  if (tid < 64) {  // lnf on row 0 -> obuf[0..255]
    float v0 = hbuf[lane], v1 = hbuf[lane + 64], v2 = hbuf[lane + 128], v3 = hbuf[lane + 192];
    float m = wave_bsum(v0 + v1 + v2 + v3) * (1.0f / 256.0f);
    float d0 = v0 - m, d1 = v1 - m, d2 = v2 - m, d3 = v3 - m;
    float var = wave_bsum(d0 * d0 + d1 * d1 + d2 * d2 + d3 * d3) * (1.0f / 256.0f);
    float rstd = 1.0f / sqrtf(var + 1e-5f);
    obuf[lane]       = d0 * rstd * lnf_g[lane]       + lnf_b[lane];
    obuf[lane + 64]  = d1 * rstd * lnf_g[lane + 64]  + lnf_b[lane + 64];
    obuf[lane + 128] = d2 * rstd * lnf_g[lane + 128] + lnf_b[lane + 128];
    obuf[lane + 192] = d3 * rstd * lnf_g[lane + 192] + lnf_b[lane + 192];
  }
  __syncthreads();
  // z_e = lnf(cls) @ W_out^T + b_out -> obuf[256..384)
  for (int o = wave; o < ED; o += 8) {
    const float4 w4 = *(const float4*)&W_out[o * DM + lane * 4];
    const float4 c4 = *(const float4*)&obuf[lane * 4];
    float s = w4.x * c4.x + w4.y * c4.y + w4.z * c4.z + w4.w * c4.w;
    s = wave_bsum(s);
    if (lane == 0) obuf[256 + o] = s + b_out[o];
  }
  __syncthreads();

  // VQ argmin over |cb|^2 - 2 ze.cb (|ze|^2 constant); first-index tie-break
  float bestv = 3.4e38f;
  int bestk = 0;
  for (int ch = 0; ch < 8; ++ch) {
    __syncthreads();
    for (int f = tid; f < 128 * 128; f += NT) {  // stage cb chunk, rows padded to 129
      int r = f >> 7, c = f & 127;
      hbuf[r * 129 + c] = codebook[(size_t)(ch * 128 + r) * ED + c];
    }
    __syncthreads();
    {
      int kl = tid & 127, q = tid >> 7;
      float part = 0.f;
#pragma unroll 8
      for (int jj = 0; jj < 32; ++jj) {
        int e = q * 32 + jj;
        float cv = hbuf[kl * 129 + e];
        part += cv * (cv - 2.0f * obuf[256 + e]);
      }
      scr[kl * 4 + q] = part;
    }
    __syncthreads();
    if (tid < 128) {
      float d2v = scr[tid * 4] + scr[tid * 4 + 1] + scr[tid * 4 + 2] + scr[tid * 4 + 3];
      int kk = ch * 128 + tid;
      if (d2v < bestv) { bestv = d2v; bestk = kk; }  // ascending k per thread
    }
  }
  if (tid < 128) {
    scr[512 + tid] = bestv;
    scr[640 + tid] = __int_as_float(bestk);
  }
  __syncthreads();
  if (tid == 0) {
    float bv = 3.4e38f;
    int bk = 1 << 30;
    for (int j = 0; j < 128; ++j) {
      float v = scr[512 + j];
      int kk = __float_as_int(scr[640 + j]);
      if (v < bv || (v == bv && kk < bk)) { bv = v; bk = kk; }
    }
    scr[700] = __int_as_float(bk);
    out[2 * NB + b] = (float)bk;  // indices output (as float value)
  }
  __syncthreads();
  const int bk = __float_as_int(scr[700]);

  // z_q -> obuf[384..512); commitment + histogram
  if (tid < ED) {
    float zqv = codebook[(size_t)bk * ED + tid];
    obuf[384 + tid] = zqv;
    float df = zqv - obuf[256 + tid];
    float sq = wave_bsum(df * df);
    if ((tid & 63) == 0) atomicAdd(&ws[0], sq);
  }
  if (tid == 0) atomicAdd(&ws[1 + bk], 1.0f);
  __syncthreads();

  // decoder: d1 = zq @ Wd1^T + bd1 (256) -> LN -> gelu -> @Wd2^T (128) -> gelu -> @Wd3^T (2)
  for (int o = wave; o < DM; o += 8) {
    const float2 w2 = *(const float2*)&Wd1[o * ED + lane * 2];
    const float2 z2 = *(const float2*)&obuf[384 + lane * 2];
    float s = wave_bsum(w2.x * z2.x + w2.y * z2.y);
    if (lane == 0) obuf[512 + o] = s + bd1[o];
  }
  __syncthreads();
  if (tid < 64) {
    float v0 = obuf[512 + lane], v1 = obuf[512 + lane + 64];
    float v2 = obuf[512 + lane + 128], v3 = obuf[512 + lane + 192];
    float m = wave_bsum(v0 + v1 + v2 + v3) * (1.0f / 256.0f);
    float d0 = v0 - m, d1 = v1 - m, d2 = v2 - m, d3 = v3 - m;
    float var = wave_bsum(d0 * d0 + d1 * d1 + d2 * d2 + d3 * d3) * (1.0f / 256.0f);
    float rstd = 1.0f / sqrtf(var + 1e-5f);
    obuf[512 + lane]       = gelu_f(d0 * rstd * lnd_g[lane]       + lnd_b[lane]);
    obuf[512 + lane + 64]  = gelu_f(d1 * rstd * lnd_g[lane + 64]  + lnd_b[lane + 64]);
    obuf[512 + lane + 128] = gelu_f(d2 * rstd * lnd_g[lane + 128] + lnd_b[lane + 128]);
    obuf[512 + lane + 192] = gelu_f(d3 * rstd * lnd_g[lane + 192] + lnd_b[lane + 192]);
  }
  __syncthreads();
  for (int o = wave; o < ED; o += 8) {
    const float4 w4 = *(const float4*)&Wd2[o * DM + lane * 4];
    const float4 g4 = *(const float4*)&obuf[512 + lane * 4];
    float s = wave_bsum(w4.x * g4.x + w4.y * g4.y + w4.z * g4.z + w4.w * g4.w);
    if (lane == 0) obuf[768 + o] = gelu_f(s + bd2[o]);
  }
  __syncthreads();
  if (wave < 2) {
    const float2 w2 = *(const float2*)&Wd3[wave * ED + lane * 2];
    const float2 g2 = *(const float2*)&obuf[768 + lane * 2];
    float s = wave_bsum(w2.x * g2.x + w2.y * g2.y);
    if (lane == 0) out[b * 2 + wave] = s + bd3[wave];
  }
}

__global__ void vqvae_finish(const float* __restrict__ ws, float* __restrict__ out) {
  __shared__ float red[256];
  int tid = threadIdx.x;
  float part = 0.f;
  for (int k = tid; k < KCB; k += 256) {
    float p = ws[1 + k] * (1.0f / 2048.0f);
    part += p * logf(p + 1e-10f);
  }
  red[tid] = part;
  __syncthreads();
  for (int s = 128; s > 0; s >>= 1) {
    if (tid < s) red[tid] += red[tid + s];
    __syncthreads();
  }
  if (tid == 0) {
    out[2 * NB + NB]     = 0.1f * ws[0] * (1.0f / (2048.0f * 128.0f));  // commitment loss
    out[2 * NB + NB + 1] = expf(-red[0]);                               // perplexity
  }
}

extern "C" void kernel_launch(void* const* d_in, const int* in_sizes, int n_in,
                              void* d_out, int out_size, void* d_ws, size_t ws_size,
                              hipStream_t stream) {
  (void)in_sizes; (void)n_in; (void)out_size; (void)ws_size;
  const float* x         = (const float*)d_in[0];
  const float* W_in      = (const float*)d_in[1];
  const float* b_in      = (const float*)d_in[2];
  const float* cls_token = (const float*)d_in[3];
  const float* Wqkv      = (const float*)d_in[4];
  const float* bqkv      = (const float*)d_in[5];
  const float* Wo        = (const float*)d_in[6];
  const float* bo        = (const float*)d_in[7];
  const float* W1        = (const float*)d_in[8];
  const float* b1        = (const float*)d_in[9];
  const float* W2        = (const float*)d_in[10];
  const float* b2        = (const float*)d_in[11];
  const float* ln1_g     = (const float*)d_in[12];
  const float* ln1_b     = (const float*)d_in[13];
  const float* ln2_g     = (const float*)d_in[14];
  const float* ln2_b     = (const float*)d_in[15];
  const float* lnf_g     = (const float*)d_in[16];
  const float* lnf_b     = (const float*)d_in[17];
  const float* W_out     = (const float*)d_in[18];
  const float* b_out     = (const float*)d_in[19];
  const float* codebook  = (const float*)d_in[20];
  const float* Wd1       = (const float*)d_in[21];
  const float* bd1       = (const float*)d_in[22];
  const float* lnd_g     = (const float*)d_in[23];
  const float* lnd_b     = (const float*)d_in[24];
  const float* Wd2       = (const float*)d_in[25];
  const float* bd2       = (const float*)d_in[26];
  const float* Wd3       = (const float*)d_in[27];
  const float* bd3       = (const float*)d_in[28];
  float* out = (float*)d_out;
  float* ws = (float*)d_ws;

  hipLaunchKernelGGL(vqvae_zero, dim3(5), dim3(256), 0, stream, ws);
  hipLaunchKernelGGL(vqvae_main, dim3(NB), dim3(NT), 0, stream,
                     x, W_in, b_in, cls_token, Wqkv, bqkv, Wo, bo, W1, b1, W2, b2,
                     ln1_g, ln1_b, ln2_g, ln2_b, lnf_g, lnf_b, W_out, b_out,
                     codebook, Wd1, bd1, lnd_g, lnd_b, Wd2, bd2, Wd3, bd3, out, ws);
  hipLaunchKernelGGL(vqvae_finish, dim3(1), dim3(256), 0, stream, ws, out);
}

// Round 9
// 15693.451 us; speedup vs baseline: 3.3865x; 1.0866x over previous
//
#include <hip/hip_runtime.h>
#include <math.h>

// Problem constants
#define NB   2048   // batch
#define SEQ  64
#define CIN  142
#define DM   256
#define NH   8
#define DHD  32
#define FFD  512
#define NL   3
#define ED   128
#define KCB  1024
#define TT   65     // SEQ+1 (cls prepended)
#define NT   512    // threads per block

__device__ __forceinline__ float gelu_f(float x) {
  return 0.5f * x * (1.0f + erff(x * 0.70710678118654752f));
}

__device__ __forceinline__ float wave_bsum(float v) {
#pragma unroll
  for (int off = 32; off >= 1; off >>= 1) v += __shfl_xor(v, off, 64);
  return v;
}
__device__ __forceinline__ float wave_bmax(float v) {
#pragma unroll
  for (int off = 32; off >= 1; off >>= 1) v = fmaxf(v, __shfl_xor(v, off, 64));
  return v;
}

// ---------- legacy register-tile GEMM (5t x OJNo), k-chunk 32, Wst pitch 36 ----------
// Used for qkv (col-major scr output constrains O to 3x32) and embed (wld=142 tail).
// SPILL MODEL (R1-R8, verified): full unroll of the k-loop lets the pre-RA scheduler
// hoist many iterations of wv/hv LDS loads; the 128-VGPR-capped allocator then spills
// acc every chunk (~68 B/thread/chunk -> tens of GB HBM scratch). "#pragma unroll 2"
// caps in-flight regs. R8 proof: WRITE_SIZE 4.07e7 KB -> 320 B, 28.7 -> 17.0 ms.
template <int OJN, int TROWS>
__device__ __forceinline__ void gemm_accum(float acc[5][4],
                                           const float* __restrict__ Wg, int wld,
                                           int rbase, int rsel,
                                           const float* src, int sld, int kdim,
                                           float* Wst, int tid) {
  constexpr int IN = (TROWS + 15) / 16;
  const int og = tid & 31, tg = tid >> 5;
  constexpr int WROWS = 32 * OJN;
  const bool v4ok = ((wld & 3) == 0);  // wave-uniform; false only for embed (wld=142)
  for (int kc = 0; kc < kdim; kc += 32) {
    const int kw = (kdim - kc < 32) ? (kdim - kc) : 32;
    __syncthreads();  // protect Wst from previous consumers
    if (kw == 32 && v4ok) {
      for (int f = tid; f < WROWS * 8; f += NT) {
        int r = f >> 3, c4 = f & 7;
        int grow = rbase + (r & 31) + rsel * (r >> 5);
        const float4 w = *(const float4*)&Wg[grow * wld + kc + c4 * 4];
        *(float4*)&Wst[r * 36 + c4 * 4] = w;
      }
    } else if (kw == 32) {
      for (int f = tid; f < WROWS * 32; f += NT) {
        int r = f >> 5, c = f & 31;
        int grow = rbase + (r & 31) + rsel * (r >> 5);
        Wst[r * 36 + c] = Wg[grow * wld + kc + c];
      }
    } else {
      for (int f = tid; f < WROWS * kw; f += NT) {
        int r = f / kw, c = f - r * kw;
        int grow = rbase + (r & 31) + rsel * (r >> 5);
        Wst[r * 36 + c] = Wg[grow * wld + kc + c];
      }
    }
    __syncthreads();
    if (kw == 32) {
#pragma unroll 2
      for (int k = 0; k < 32; k += 4) {
        float4 wv[OJN];
#pragma unroll
        for (int oj = 0; oj < OJN; ++oj)
          wv[oj] = *(const float4*)&Wst[(og + 32 * oj) * 36 + k];
#pragma unroll
        for (int i = 0; i < IN; ++i) {
          int t = tg + 16 * i;
          if (i < IN - 1 || t < TROWS) {
            float4 hv = *(const float4*)&src[t * sld + kc + k];
#pragma unroll
            for (int oj = 0; oj < OJN; ++oj)
              acc[i][oj] += hv.x * wv[oj].x + hv.y * wv[oj].y +
                            hv.z * wv[oj].z + hv.w * wv[oj].w;
          }
        }
      }
    } else {  // tail (only embed: kw=14, even) - float2 path
#pragma unroll 2
      for (int k = 0; k < kw; k += 2) {
        float2 wv[OJN];
#pragma unroll
        for (int oj = 0; oj < OJN; ++oj)
          wv[oj] = *(const float2*)&Wst[(og + 32 * oj) * 36 + k];
#pragma unroll
        for (int i = 0; i < IN; ++i) {
          int t = tg + 16 * i;
          if (i < IN - 1 || t < TROWS) {
            float2 hv = *(const float2*)&src[t * sld + kc + k];
#pragma unroll
            for (int oj = 0; oj < OJN; ++oj)
              acc[i][oj] += hv.x * wv[oj].x + hv.y * wv[oj].y;
          }
        }
      }
    }
  }
}

// ---------- wide-tile GEMM: 5t x 8o (256 cols/call), k-chunk 16, Wst pitch 20 ----------
// R8 showed the gemm inner loop is LDS-BW-bound (VALUBusy 54% == 320/576 model).
// Tile ratio 2(T+O)/(T*O): 5x4 = 0.9 B/FLOP -> 5x8 = 0.65 B/FLOP (1.38x on LDS time).
// k-chunk 16 so Wst (256 rows x 20) = 5120 floats fits scr. Pitch 20 is
// bank-balanced for b128 reads (word-bank histogram uniform). k-loop is
// "#pragma unroll 1": in-flight = acc 40 + wv 32 + hv <=20 + addr < 128 (no spill).
template <int TROWS>
__device__ __forceinline__ void gemm8(float (*acc)[8],
                                      const float* __restrict__ Wg, int wld, int rbase,
                                      const float* src, int sld, int kdim,
                                      float* Wst, int tid) {
  constexpr int IN = (TROWS + 15) / 16;
  const int og = tid & 31, tg = tid >> 5;
  const int sr = tid >> 2;          // staging row (0..127), +128 for e=1
  const int sc = (tid & 3) * 4;     // staging col (float index)
  for (int kc = 0; kc < kdim; kc += 16) {
    __syncthreads();  // Wst free
#pragma unroll
    for (int e = 0; e < 2; ++e) {
      int r = sr + e * 128;
      *(float4*)&Wst[r * 20 + sc] = *(const float4*)&Wg[(rbase + r) * wld + kc + sc];
    }
    __syncthreads();  // Wst ready
#pragma unroll 1
    for (int k = 0; k < 16; k += 4) {
      float4 wv[8];
#pragma unroll
      for (int oj = 0; oj < 8; ++oj)
        wv[oj] = *(const float4*)&Wst[(og + 32 * oj) * 20 + k];
#pragma unroll
      for (int i = 0; i < IN; ++i) {
        int t = tg + 16 * i;
        if (i < IN - 1 || t < TROWS) {
          float4 hv = *(const float4*)&src[t * sld + kc + k];
#pragma unroll
          for (int oj = 0; oj < 8; ++oj)
            acc[i][oj] += hv.x * wv[oj].x + hv.y * wv[oj].y +
                          hv.z * wv[oj].z + hv.w * wv[oj].w;
        }
      }
    }
  }
}

__device__ __forceinline__ void ln_rows(float* buf, const float* g, const float* be,
                                        int wave, int lane) {
  for (int t = wave; t < TT; t += 8) {
    float v0 = buf[t * DM + lane],       v1 = buf[t * DM + lane + 64];
    float v2 = buf[t * DM + lane + 128], v3 = buf[t * DM + lane + 192];
    float m = wave_bsum(v0 + v1 + v2 + v3) * (1.0f / 256.0f);
    float d0 = v0 - m, d1 = v1 - m, d2 = v2 - m, d3 = v3 - m;
    float var = wave_bsum(d0 * d0 + d1 * d1 + d2 * d2 + d3 * d3) * (1.0f / 256.0f);
    float rstd = 1.0f / sqrtf(var + 1e-5f);
    buf[t * DM + lane]       = d0 * rstd * g[lane]       + be[lane];
    buf[t * DM + lane + 64]  = d1 * rstd * g[lane + 64]  + be[lane + 64];
    buf[t * DM + lane + 128] = d2 * rstd * g[lane + 128] + be[lane + 128];
    buf[t * DM + lane + 192] = d3 * rstd * g[lane + 192] + be[lane + 192];
  }
}

__global__ void vqvae_zero(float* __restrict__ ws) {
  int i = blockIdx.x * blockDim.x + threadIdx.x;
  if (i < 1025) ws[i] = 0.f;
}

// LDS (161,216 B) limits to 1 block/CU = 8 waves = 2 waves/SIMD.
__global__ __attribute__((amdgpu_flat_work_group_size(512, 512), amdgpu_waves_per_eu(2)))
void vqvae_main(
    const float* __restrict__ x, const float* __restrict__ W_in,
    const float* __restrict__ b_in, const float* __restrict__ cls_token,
    const float* __restrict__ Wqkv, const float* __restrict__ bqkv,
    const float* __restrict__ Wo, const float* __restrict__ bo,
    const float* __restrict__ W1, const float* __restrict__ b1,
    const float* __restrict__ W2, const float* __restrict__ b2,
    const float* __restrict__ ln1_g, const float* __restrict__ ln1_b,
    const float* __restrict__ ln2_g, const float* __restrict__ ln2_b,
    const float* __restrict__ lnf_g, const float* __restrict__ lnf_b,
    const float* __restrict__ W_out, const float* __restrict__ b_out,
    const float* __restrict__ codebook, const float* __restrict__ Wd1,
    const float* __restrict__ bd1, const float* __restrict__ lnd_g,
    const float* __restrict__ lnd_b, const float* __restrict__ Wd2,
    const float* __restrict__ bd2, const float* __restrict__ Wd3,
    const float* __restrict__ bd3, float* __restrict__ out,
    float* __restrict__ ws) {
  // 161,216 B static LDS (gfx950: 163,840 B available)
  __shared__ __align__(16) float hbuf[TT * DM];  // residual stream; later: codebook chunk [128][129]
  __shared__ __align__(16) float obuf[16896];    // x-stage / attn-out / FF f1 [<=33][512] / head scalars
  __shared__ __align__(16) float scr[6768];      // Wstage (<=256x20 | <=128x36) | qkv col-major [96][65] + p rows

  const int tid = threadIdx.x;
  const int b = blockIdx.x;
  const int lane = tid & 63, wave = tid >> 6;
  const int og = tid & 31, tg = tid >> 5;

  // ---------------- embed: h[0]=cls, h[1+r] = x[r] @ W_in^T + b_in + PE[r] ----------------
  for (int f = tid; f < SEQ * CIN; f += NT) {  // stage x[b] into obuf, rows padded to 144
    int r = f / CIN, c = f - r * CIN;
    obuf[r * 144 + c] = x[(size_t)b * (SEQ * CIN) + f];
  }
  if (tid < DM) hbuf[tid] = cls_token[tid];
  __syncthreads();

  for (int oc = 0; oc < 2; ++oc) {
    float acc[5][4] = {{0.f}};
    gemm_accum<4, 64>(acc, W_in, CIN, oc * 128, 32, obuf, 144, CIN, scr, tid);
#pragma unroll
    for (int i = 0; i < 4; ++i) {
      int r = tg + 16 * i;
#pragma unroll
      for (int oj = 0; oj < 4; ++oj) {
        int d = oc * 128 + og + 32 * oj;
        float div = expf(-(float)(d & ~1) * (9.210340371976184f / 256.0f));
        float ang = (float)r * div;
        float pe = (d & 1) ? cosf(ang) : sinf(ang);
        hbuf[(r + 1) * DM + d] = acc[i][oj] + b_in[d] + pe;
      }
    }
  }
  __syncthreads();

  // ---------------- transformer layers ----------------
  for (int li = 0; li < NL; ++li) {
    const float* Wqkv_l = Wqkv + (size_t)li * 768 * DM;
    const float* bqkv_l = bqkv + li * 768;
    const float* Wo_l = Wo + (size_t)li * DM * DM;
    const float* bo_l = bo + li * DM;
    const float* W1_l = W1 + (size_t)li * FFD * DM;
    const float* b1_l = b1 + li * FFD;
    const float* W2_l = W2 + (size_t)li * DM * FFD;
    const float* b2_l = b2 + li * DM;

    // ---- attention (per head): qkv GEMM -> col-major scr, online softmax, o -> obuf ----
    for (int hd = 0; hd < NH; ++hd) {
      float acc[5][4] = {{0.f}};
      // rows: q=hd*32+og (oj=0), k=256+hd*32+og (oj=1), v=512+hd*32+og (oj=2)
      gemm_accum<3, 65>(acc, Wqkv_l, DM, hd * 32, 256, hbuf, DM, DM, scr, tid);
      __syncthreads();  // all Wst reads done before qkv overwrites scr
#pragma unroll
      for (int i = 0; i < 5; ++i) {
        int t = tg + 16 * i;
        if (t < TT) {
#pragma unroll
          for (int oj = 0; oj < 3; ++oj)
            scr[(og + 32 * oj) * TT + t] = acc[i][oj] + bqkv_l[oj * 256 + hd * 32 + og];
        }
      }
      __syncthreads();

      // scores: lane=u(0..63), rows t = wave+8*it; u=64 handled via reduced partial
      float sv[9];
#pragma unroll
      for (int it = 0; it < 9; ++it) sv[it] = 0.f;
#pragma unroll 4
      for (int j = 0; j < 32; ++j) {
        float kv = scr[(32 + j) * TT + lane];  // k[lane][j]
#pragma unroll
        for (int it = 0; it < 9; ++it) {
          int t = wave + 8 * it;
          if (it < 8 || t < TT) sv[it] += scr[j * TT + t] * kv;  // q[t][j] broadcast
        }
      }
#pragma unroll
      for (int it = 0; it < 9; ++it) {
        int t = wave + 8 * it;
        if (t < TT) {  // wave-uniform guard
          int jj = lane & 31;
          float p64 = scr[jj * TT + t] * scr[(32 + jj) * TT + 64] * 0.5f;  // halves dup -> *0.5
          p64 = wave_bsum(p64);
          const float sc = 0.17677669529663687f;  // 1/sqrt(32)
          float s = sv[it] * sc, s64 = p64 * sc;
          float m = fmaxf(wave_bmax(s), s64);
          float e = expf(s - m), e64 = expf(s64 - m);
          float inv = 1.0f / (wave_bsum(e) + e64);
          float* prow = &scr[96 * TT + wave * 66];
          prow[lane] = e * inv;
          if (lane == 0) prow[64] = e64 * inv;
          // o[t][e] = sum_u p[u] * v[u][e]; lanes (e, u-half)
          int e_ = lane & 31, half = lane >> 5;
          float o = 0.f;
          int u0 = half * 33, u1 = half ? 65 : 33;
#pragma unroll 4
          for (int u = u0; u < u1; ++u) o += prow[u] * scr[(64 + e_) * TT + u];
          o += __shfl_down(o, 32, 64);
          if (lane < 32) obuf[t * DM + hd * 32 + e_] = o;
        }
      }
      __syncthreads();  // before next head re-stages scr
    }

    // ---- proj + residual: h += o @ Wo^T + bo (one 256-col wide-tile call); LN1 ----
    {
      float acc[5][8] = {{0.f}};
      gemm8<65>(acc, Wo_l, DM, 0, obuf, DM, DM, scr, tid);
#pragma unroll
      for (int i = 0; i < 5; ++i) {
        int t = tg + 16 * i;
        if (t < TT) {
#pragma unroll
          for (int oj = 0; oj < 8; ++oj) {
            int d = og + 32 * oj;
            hbuf[t * DM + d] += acc[i][oj] + bo_l[d];
          }
        }
      }
    }
    __syncthreads();
    ln_rows(hbuf, ln1_g + li * DM, ln1_b + li * DM, wave, lane);
    __syncthreads();

    // ---- FF: T-split two-pass (f1 storage bound); wide-tile gemms ----
    // pass 0: rows [0,32), pass 1: rows [32,65). f1 (full 512 cols) in obuf [nr][512].
    // W2 = one K=512, 256-col call per pass, writing ff+u+b2 into this pass's hbuf
    // rows (disjoint from the u rows the other pass's W1 still needs).
    for (int ps = 0; ps < 2; ++ps) {
      const int r0 = ps ? 32 : 0;
      const int nr = ps ? 33 : 32;
      for (int cc = 0; cc < 2; ++cc) {  // f1 cols [cc*256, cc*256+256)
        if (ps == 0) {
          float acc[2][8] = {{0.f}};
          gemm8<32>(acc, W1_l, DM, cc * 256, hbuf + r0 * DM, DM, DM, scr, tid);
#pragma unroll
          for (int i = 0; i < 2; ++i) {
            int t = tg + 16 * i;
#pragma unroll
            for (int oj = 0; oj < 8; ++oj) {
              int m = cc * 256 + og + 32 * oj;
              obuf[t * FFD + m] = gelu_f(acc[i][oj] + b1_l[m]);
            }
          }
        } else {
          float acc[3][8] = {{0.f}};
          gemm8<33>(acc, W1_l, DM, cc * 256, hbuf + r0 * DM, DM, DM, scr, tid);
#pragma unroll
          for (int i = 0; i < 3; ++i) {
            int t = tg + 16 * i;
            if (t < 33) {
#pragma unroll
              for (int oj = 0; oj < 8; ++oj) {
                int m = cc * 256 + og + 32 * oj;
                obuf[t * FFD + m] = gelu_f(acc[i][oj] + b1_l[m]);
              }
            }
          }
        }
      }
      if (ps == 0) {
        float acc[2][8] = {{0.f}};
        gemm8<32>(acc, W2_l, FFD, 0, obuf, FFD, FFD, scr, tid);
#pragma unroll
        for (int i = 0; i < 2; ++i) {
          int t = tg + 16 * i;
#pragma unroll
          for (int oj = 0; oj < 8; ++oj) {
            int d = og + 32 * oj;
            int gi = (r0 + t) * DM + d;
            hbuf[gi] = hbuf[gi] + acc[i][oj] + b2_l[d];
          }
        }
      } else {
        float acc[3][8] = {{0.f}};
        gemm8<33>(acc, W2_l, FFD, 0, obuf, FFD, FFD, scr, tid);
#pragma unroll
        for (int i = 0; i < 3; ++i) {
          int t = tg + 16 * i;
          if (t < 33) {
#pragma unroll
            for (int oj = 0; oj < 8; ++oj) {
              int d = og + 32 * oj;
              int gi = (r0 + t) * DM + d;
              hbuf[gi] = hbuf[gi] + acc[i][oj] + b2_l[d];
            }
          }
        }
      }
    }
    __syncthreads();
    ln_rows(hbuf, ln2_g + li * DM, ln2_b + li * DM, wave, lane);
    __syncthreads();
  }

  // ---------------- head: lnf(cls) -> z_e -> VQ argmin -> decoder ----------------
  if (tid < 64) {  // lnf on row 0 -> obuf[0..255]
    float v0 = hbuf[lane], v1 = hbuf[lane + 64], v2 = hbuf[lane + 128], v3 = hbuf[lane + 192];
    float m = wave_bsum(v0 + v1 + v2 + v3) * (1.0f / 256.0f);
    float d0 = v0 - m, d1 = v1 - m, d2 = v2 - m, d3 = v3 - m;
    float var = wave_bsum(d0 * d0 + d1 * d1 + d2 * d2 + d3 * d3) * (1.0f / 256.0f);
    float rstd = 1.0f / sqrtf(var + 1e-5f);
    obuf[lane]       = d0 * rstd * lnf_g[lane]       + lnf_b[lane];
    obuf[lane + 64]  = d1 * rstd * lnf_g[lane + 64]  + lnf_b[lane + 64];
    obuf[lane + 128] = d2 * rstd * lnf_g[lane + 128] + lnf_b[lane + 128];
    obuf[lane + 192] = d3 * rstd * lnf_g[lane + 192] + lnf_b[lane + 192];
  }
  __syncthreads();
  // z_e = lnf(cls) @ W_out^T + b_out -> obuf[256..384)
  for (int o = wave; o < ED; o += 8) {
    const float4 w4 = *(const float4*)&W_out[o * DM + lane * 4];
    const float4 c4 = *(const float4*)&obuf[lane * 4];
    float s = w4.x * c4.x + w4.y * c4.y + w4.z * c4.z + w4.w * c4.w;
    s = wave_bsum(s);
    if (lane == 0) obuf[256 + o] = s + b_out[o];
  }
  __syncthreads();

  // VQ argmin over |cb|^2 - 2 ze.cb (|ze|^2 constant); first-index tie-break
  float bestv = 3.4e38f;
  int bestk = 0;
  for (int ch = 0; ch < 8; ++ch) {
    __syncthreads();
    for (int f = tid; f < 128 * 128; f += NT) {  // stage cb chunk, rows padded to 129
      int r = f >> 7, c = f & 127;
      hbuf[r * 129 + c] = codebook[(size_t)(ch * 128 + r) * ED + c];
    }
    __syncthreads();
    {
      int kl = tid & 127, q = tid >> 7;
      float part = 0.f;
#pragma unroll 8
      for (int jj = 0; jj < 32; ++jj) {
        int e = q * 32 + jj;
        float cv = hbuf[kl * 129 + e];
        part += cv * (cv - 2.0f * obuf[256 + e]);
      }
      scr[kl * 4 + q] = part;
    }
    __syncthreads();
    if (tid < 128) {
      float d2v = scr[tid * 4] + scr[tid * 4 + 1] + scr[tid * 4 + 2] + scr[tid * 4 + 3];
      int kk = ch * 128 + tid;
      if (d2v < bestv) { bestv = d2v; bestk = kk; }  // ascending k per thread
    }
  }
  if (tid < 128) {
    scr[512 + tid] = bestv;
    scr[640 + tid] = __int_as_float(bestk);
  }
  __syncthreads();
  if (tid == 0) {
    float bv = 3.4e38f;
    int bk = 1 << 30;
    for (int j = 0; j < 128; ++j) {
      float v = scr[512 + j];
      int kk = __float_as_int(scr[640 + j]);
      if (v < bv || (v == bv && kk < bk)) { bv = v; bk = kk; }
    }
    scr[700] = __int_as_float(bk);
    out[2 * NB + b] = (float)bk;  // indices output (as float value)
  }
  __syncthreads();
  const int bk = __float_as_int(scr[700]);

  // z_q -> obuf[384..512); commitment + histogram
  if (tid < ED) {
    float zqv = codebook[(size_t)bk * ED + tid];
    obuf[384 + tid] = zqv;
    float df = zqv - obuf[256 + tid];
    float sq = wave_bsum(df * df);
    if ((tid & 63) == 0) atomicAdd(&ws[0], sq);
  }
  if (tid == 0) atomicAdd(&ws[1 + bk], 1.0f);
  __syncthreads();

  // decoder: d1 = zq @ Wd1^T + bd1 (256) -> LN -> gelu -> @Wd2^T (128) -> gelu -> @Wd3^T (2)
  for (int o = wave; o < DM; o += 8) {
    const float2 w2 = *(const float2*)&Wd1[o * ED + lane * 2];
    const float2 z2 = *(const float2*)&obuf[384 + lane * 2];
    float s = wave_bsum(w2.x * z2.x + w2.y * z2.y);
    if (lane == 0) obuf[512 + o] = s + bd1[o];
  }
  __syncthreads();
  if (tid < 64) {
    float v0 = obuf[512 + lane], v1 = obuf[512 + lane + 64];
    float v2 = obuf[512 + lane + 128], v3 = obuf[512 + lane + 192];
    float m = wave_bsum(v0 + v1 + v2 + v3) * (1.0f / 256.0f);
    float d0 = v0 - m, d1 = v1 - m, d2 = v2 - m, d3 = v3 - m;
    float var = wave_bsum(d0 * d0 + d1 * d1 + d2 * d2 + d3 * d3) * (1.0f / 256.0f);
    float rstd = 1.0f / sqrtf(var + 1e-5f);
    obuf[512 + lane]       = gelu_f(d0 * rstd * lnd_g[lane]       + lnd_b[lane]);
    obuf[512 + lane + 64]  = gelu_f(d1 * rstd * lnd_g[lane + 64]  + lnd_b[lane + 64]);
    obuf[512 + lane + 128] = gelu_f(d2 * rstd * lnd_g[lane + 128] + lnd_b[lane + 128]);
    obuf[512 + lane + 192] = gelu_f(d3 * rstd * lnd_g[lane + 192] + lnd_b[lane + 192]);
  }
  __syncthreads();
  for (int o = wave; o < ED; o += 8) {
    const float4 w4 = *(const float4*)&Wd2[o * DM + lane * 4];
    const float4 g4 = *(const float4*)&obuf[512 + lane * 4];
    float s = wave_bsum(w4.x * g4.x + w4.y * g4.y + w4.z * g4.z + w4.w * g4.w);
    if (lane == 0) obuf[768 + o] = gelu_f(s + bd2[o]);
  }
  __syncthreads();
  if (wave < 2) {
    const float2 w2 = *(const float2*)&Wd3[wave * ED + lane * 2];
    const float2 g2 = *(const float2*)&obuf[768 + lane * 2];
    float s = wave_bsum(w2.x * g2.x + w2.y * g2.y);
    if (lane == 0) out[b * 2 + wave] = s + bd3[wave];
  }
}

__global__ void vqvae_finish(const float* __restrict__ ws, float* __restrict__ out) {
  __shared__ float red[256];
  int tid = threadIdx.x;
  float part = 0.f;
  for (int k = tid; k < KCB; k += 256) {
    float p = ws[1 + k] * (1.0f / 2048.0f);
    part += p * logf(p + 1e-10f);
  }
  red[tid] = part;
  __syncthreads();
  for (int s = 128; s > 0; s >>= 1) {
    if (tid < s) red[tid] += red[tid + s];
    __syncthreads();
  }
  if (tid == 0) {
    out[2 * NB + NB]     = 0.1f * ws[0] * (1.0f / (2048.0f * 128.0f));  // commitment loss
    out[2 * NB + NB + 1] = expf(-red[0]);                               // perplexity
  }
}

extern "C" void kernel_launch(void* const* d_in, const int* in_sizes, int n_in,
                              void* d_out, int out_size, void* d_ws, size_t ws_size,
                              hipStream_t stream) {
  (void)in_sizes; (void)n_in; (void)out_size; (void)ws_size;
  const float* x         = (const float*)d_in[0];
  const float* W_in      = (const float*)d_in[1];
  const float* b_in      = (const float*)d_in[2];
  const float* cls_token = (const float*)d_in[3];
  const float* Wqkv      = (const float*)d_in[4];
  const float* bqkv      = (const float*)d_in[5];
  const float* Wo        = (const float*)d_in[6];
  const float* bo        = (const float*)d_in[7];
  const float* W1        = (const float*)d_in[8];
  const float* b1        = (const float*)d_in[9];
  const float* W2        = (const float*)d_in[10];
  const float* b2        = (const float*)d_in[11];
  const float* ln1_g     = (const float*)d_in[12];
  const float* ln1_b     = (const float*)d_in[13];
  const float* ln2_g     = (const float*)d_in[14];
  const float* ln2_b     = (const float*)d_in[15];
  const float* lnf_g     = (const float*)d_in[16];
  const float* lnf_b     = (const float*)d_in[17];
  const float* W_out     = (const float*)d_in[18];
  const float* b_out     = (const float*)d_in[19];
  const float* codebook  = (const float*)d_in[20];
  const float* Wd1       = (const float*)d_in[21];
  const float* bd1       = (const float*)d_in[22];
  const float* lnd_g     = (const float*)d_in[23];
  const float* lnd_b     = (const float*)d_in[24];
  const float* Wd2       = (const float*)d_in[25];
  const float* bd2       = (const float*)d_in[26];
  const float* Wd3       = (const float*)d_in[27];
  const float* bd3       = (const float*)d_in[28];
  float* out = (float*)d_out;
  float* ws = (float*)d_ws;

  hipLaunchKernelGGL(vqvae_zero, dim3(5), dim3(256), 0, stream, ws);
  hipLaunchKernelGGL(vqvae_main, dim3(NB), dim3(NT), 0, stream,
                     x, W_in, b_in, cls_token, Wqkv, bqkv, Wo, bo, W1, b1, W2, b2,
                     ln1_g, ln1_b, ln2_g, ln2_b, lnf_g, lnf_b, W_out, b_out,
                     codebook, Wd1, bd1, lnd_g, lnd_b, Wd2, bd2, Wd3, bd3, out, ws);
  hipLaunchKernelGGL(vqvae_finish, dim3(1), dim3(256), 0, stream, ws, out);
}